// Round 5
// baseline (347.984 us; speedup 1.0000x reference)
//
#include <hip/hip_runtime.h>
#include <math.h>

typedef _Float16 f16;
typedef f16  f16x8 __attribute__((ext_vector_type(8)));
typedef float f32x4 __attribute__((ext_vector_type(4)));
typedef unsigned short ushort_t;

#define MFMA16(a, b, c) __builtin_amdgcn_mfma_f32_16x16x32_f16((a), (b), (c), 0, 0, 0)

// ---------------- workspace layout (f16 element offsets) ----------------
#define W1T_E 0        // [256][480]  vae_W1^T
#define WZV_E 122880   // [48][256]   [vae_Wz | vae_Wv | 0]^T
#define A1T_E 135168   // [64][96]    ae_W1^T
#define A2T_E 141312   // [32][64]    ae_W2^T
#define G1T_E 143360   // [64][32]    gate_W1^T
#define G2T_E 145408   // [16][64]    gate_W2^T (cols 5..15 zero)
#define E1T_E 146432   // [5][128][192] eW1^T, K remapped to padded-192 layout
#define E2T_E 269312   // [5][128][128] eW2^T
#define E3T_E 351232   // [5][32][128]  eW3^T, cols 29..31 zero
#define F32_B 743424   // byte offset of f32 appendix:
                       //   [0..47]   BZV  = [vae_bz | vae_bv | 0]
                       //   [48..207] EB3P = eb3 padded [5][32]
                       //   [208..223]GB2P = gate_b2 padded [16]

// ---------------- LDS layout (bytes), 48-row tile (3 blocks/CU) ----------------
// buf0 = expert input, K padded to 192 (stride 200):
//   cols 0..4 zero | 5..7 term0(f4) | 8..103 frame(96) | 104..106 v_pred |107 zero
//   | 108..139 z_H | 140..143 zero | 144..175 z_E | 176..191 zero
#define B0_OFF  0       // [48][200] f16 = 19200 (whole kernel)
#define SA_OFF  19200   // slotA [48][104] f16 = 9984: ET (pre-G3) then B1 odd frames
#define HA_OFF  29184   // [48][72]  f16 = 6912 (G3..gateL; disjoint from slotA)
#define H_OFF   19200   // [48][264] f16 = 25344 (written G1-end; slotA/HA dead)
#define H1_OFF  19200   // [48][136] f16 = 13056 (experts; sH dead after G2)
#define H2_OFF  32256   // [48][136] f16 = 13056
#define W_OFF   45312   // [48][8]   f32 = 1536  gate weights
#define MAP_OFF 46848   // 96 u32 column map (byte base in x row)
#define SMEM_SZ 47232   // 3 x 47232 = 141696 <= 163840 -> 3 blocks/CU

__device__ __forceinline__ float elu_f(float v) {
    float e = __expf(v) - 1.f;
    return v > 0.f ? v : e;
}

// round-to-nearest f32x2 -> packed f16x2 (RTZ pkrtz biased the 5-stage chain; keep RTN)
__device__ __forceinline__ unsigned pk(float a, float b) {
    ushort_t u0 = __builtin_bit_cast(ushort_t, (f16)a);
    ushort_t u1 = __builtin_bit_cast(ushort_t, (f16)b);
    return (unsigned)u0 | ((unsigned)u1 << 16);
}

__device__ __forceinline__ void store4(f16* p, f32x4 v) {
    uint2 t; t.x = pk(v[0], v[1]); t.y = pk(v[2], v[3]);
    *(uint2*)p = t;
}

__device__ __forceinline__ void elu_store4(f16* p, f32x4 v) {
    uint2 t; t.x = pk(elu_f(v[0]), elu_f(v[1])); t.y = pk(elu_f(v[2]), elu_f(v[3]));
    *(uint2*)p = t;
}

// ---------------- weight repack: fp32 -> f16, transposed/padded ----------------
__global__ void prep_kernel(const float* __restrict__ vW1, const float* __restrict__ vWz,
                            const float* __restrict__ vWv, const float* __restrict__ aW1,
                            const float* __restrict__ aW2, const float* __restrict__ gW1,
                            const float* __restrict__ gW2, const float* __restrict__ eW1,
                            const float* __restrict__ eW2, const float* __restrict__ eW3,
                            const float* __restrict__ vbz, const float* __restrict__ vbv,
                            const float* __restrict__ eb3, const float* __restrict__ gb2,
                            char* __restrict__ ws)
{
    int i = blockIdx.x * 256 + threadIdx.x;
    f16* H = (f16*)ws;
    if (i < 122880) {                                   // W1T [c=256][k=480]
        int c = i / 480, k = i - c * 480;
        H[i] = (f16)vW1[k * 256 + c];
    } else if (i < 135168) {                            // WZV [c=48][k=256]
        int j = i - 122880; int c = j / 256, k = j - c * 256;
        float v = (c < 32) ? vWz[k * 32 + c] : ((c < 35) ? vWv[k * 3 + (c - 32)] : 0.f);
        H[i] = (f16)v;
    } else if (i < 141312) {                            // A1T [c=64][k=96]
        int j = i - 135168; int c = j / 96, k = j - c * 96;
        H[i] = (f16)aW1[k * 64 + c];
    } else if (i < 143360) {                            // A2T [c=32][k=64]
        int j = i - 141312; int c = j / 64, k = j - c * 64;
        H[i] = (f16)aW2[k * 32 + c];
    } else if (i < 145408) {                            // G1T [c=64][k=32]
        int j = i - 143360; int c = j / 32, k = j - c * 32;
        H[i] = (f16)gW1[k * 64 + c];
    } else if (i < 146432) {                            // G2T [c=16][k=64]
        int j = i - 145408; int c = j / 64, k = j - c * 64;
        H[i] = (f16)((c < 5) ? gW2[k * 5 + c] : 0.f);
    } else if (i < 269312) {                            // E1T [e][c=128][k=192] remapped
        int j = i - 146432; int e = j / 24576, jj = j - e * 24576;
        int c = jj / 192, k = jj - c * 192;
        int ko = (k >= 5 && k < 107)   ? (k - 5)
               : (k >= 108 && k < 140) ? (k - 6)
               : (k >= 144 && k < 176) ? (k - 10) : -1;
        H[i] = (f16)((ko >= 0) ? eW1[(e * 166 + ko) * 128 + c] : 0.f);
    } else if (i < 351232) {                            // E2T [e][c=128][k=128]
        int j = i - 269312; int e = j / 16384, jj = j - e * 16384;
        int c = jj / 128, k = jj - c * 128;
        H[i] = (f16)eW2[(e * 128 + k) * 128 + c];
    } else if (i < 371712) {                            // E3T [e][c=32][k=128]
        int j = i - 351232; int e = j / 4096, jj = j - e * 4096;
        int c = jj / 128, k = jj - c * 128;
        H[i] = (f16)((c < 29) ? eW3[(e * 128 + k) * 29 + c] : 0.f);
    } else if (i < 371936) {                            // f32 appendix
        int j = i - 371712;
        float* F = (float*)(ws + F32_B);
        float v;
        if (j < 48)       v = (j < 32) ? vbz[j] : ((j < 35) ? vbv[j - 32] : 0.f);
        else if (j < 208) { int t = j - 48; int e = t >> 5, c = t & 31;
                            v = (c < 29) ? eb3[e * 29 + c] : 0.f; }
        else              { int t = j - 208; v = (t < 5) ? gb2[t] : 0.f; }
        F[j] = v;
    }
}

// ---------------- fused actor, 48 rows/block ----------------
__global__ __launch_bounds__(256, 3) void moe_fused(
    const float* __restrict__ x,
    const float* __restrict__ vb1,
    const float* __restrict__ ab1,
    const float* __restrict__ ab2,
    const float* __restrict__ gb1,
    const float* __restrict__ eb1,
    const float* __restrict__ eb2,
    const char* __restrict__ ws,
    float* __restrict__ out,
    int n)
{
    __shared__ __align__(16) char smem[SMEM_SZ];
    const int tid  = threadIdx.x;
    const int wv   = tid >> 6;
    const int lane = tid & 63;
    const int lr   = lane & 15;
    const int lg   = lane >> 4;
    const int row0 = (int)blockIdx.x * 48;

    const f16* W1T = (const f16*)ws + W1T_E;
    const f16* WZV = (const f16*)ws + WZV_E;
    const f16* A1T = (const f16*)ws + A1T_E;
    const f16* A2T = (const f16*)ws + A2T_E;
    const f16* G1T = (const f16*)ws + G1T_E;
    const f16* G2T = (const f16*)ws + G2T_E;
    const f16* E1T = (const f16*)ws + E1T_E;
    const f16* E2T = (const f16*)ws + E2T_E;
    const f16* E3T = (const f16*)ws + E3T_E;
    const float* BZV  = (const float*)(ws + F32_B);
    const float* EB3P = BZV + 48;
    const float* GB2P = BZV + 208;

    f16* sB0 = (f16*)(smem + B0_OFF);
    f16* sB1 = (f16*)(smem + SA_OFF);
    f16* sEt = (f16*)(smem + SA_OFF);
    f16* sHA = (f16*)(smem + HA_OFF);
    f16* sH  = (f16*)(smem + H_OFF);
    f16* sH1 = (f16*)(smem + H1_OFF);
    f16* sH2 = (f16*)(smem + H2_OFF);
    float* sWf = (float*)(smem + W_OFF);
    unsigned* smap = (unsigned*)(smem + MAP_OFF);

    const char* xc = (const char*)x;
    const int srow = tid >> 2;            // staging row 0..47 (tid < 192)
    const int cb   = 24 * (tid & 3);      // staging col base (of 96)
    const bool lowc = ((tid & 3) == 0);
    const bool stg  = (tid < 192);
    const int grow  = min(row0 + srow, n - 1);   // row-clamped (edge block)

    // ---- phase 0: srcmap, zero-init buf0 special cols, term0, e_t ----
    if (tid < 96) {
        int c = tid; int base;
        if (c < 9)       { int t = c / 3; base = 15 + 12 * t + c; }
        else if (c < 38) base = 51 + c;
        else if (c < 67) base = 167 + c;
        else             base = 283 + c;
        smap[c] = (unsigned)(base * 4);
    }
    if (tid < 48) {
        f16* rp = sB0 + tid * 200;
        uint2 z2; z2.x = 0u; z2.y = 0u;
        *(uint2*)(rp + 0) = z2; rp[4] = (f16)0.f;       // cols 0..4
        *(uint2*)(rp + 140) = z2;                       // cols 140..143
        uint4 z4; z4.x = z4.y = z4.z = z4.w = 0u;
        *(uint4*)(rp + 176) = z4; *(uint4*)(rp + 184) = z4; // cols 176..191
    }
    if (tid < 144) {
        int r = tid / 3, c = tid - 3 * r;
        int gr = min(row0 + r, n - 1);
        sB0[r * 200 + 5 + c] = (f16)x[(size_t)gr * 975 + 12 + c];
    }
    if (stg) {   // e_t -> sEt
        const float* xr = x + (size_t)grow * 975 + 879 + cb;
        f16* dst = sEt + srow * 104 + cb;
#pragma unroll
        for (int k = 0; k < 24; k += 2) {
            *(unsigned*)(dst + k) = pk(xr[k], xr[k + 1]);
        }
    }
    __syncthreads();

    // ---- G3: ha = elu(e_t @ ae_W1 + ae_b1)  [48 rows x 64 cols], K=96 ----
    {
        f32x4 bi = *(const f32x4*)(ab1 + 16 * wv + 4 * lg);
        f32x4 acc[3];
#pragma unroll
        for (int m = 0; m < 3; ++m) acc[m] = bi;
#pragma unroll
        for (int ks = 0; ks < 3; ++ks) {
            f16x8 wf = *(const f16x8*)(A1T + (16 * wv + lr) * 96 + 32 * ks + 8 * lg);
#pragma unroll
            for (int m = 0; m < 3; ++m) {
                f16x8 bf = *(const f16x8*)(sEt + (16 * m + lr) * 104 + 32 * ks + 8 * lg);
                acc[m] = MFMA16(wf, bf, acc[m]);
            }
        }
#pragma unroll
        for (int m = 0; m < 3; ++m)
            elu_store4(sHA + (16 * m + lr) * 72 + 16 * wv + 4 * lg, acc[m]);
    }
    // init staging offsets (srcmap written phase 0, synced)
    unsigned a_off[24];
    {
        unsigned rowb = (unsigned)grow * 3900u;
#pragma unroll
        for (int i = 0; i < 24; ++i) a_off[i] = rowb + smap[cb + i];
    }
    __syncthreads();

    // ---- phase A: G4 (waves 0,1) + stage frame0 -> buf0 ----
    if (wv < 2) {
        f32x4 bi = *(const f32x4*)(ab2 + 16 * wv + 4 * lg);
        f32x4 acc[3];
#pragma unroll
        for (int m = 0; m < 3; ++m) acc[m] = bi;
#pragma unroll
        for (int ks = 0; ks < 2; ++ks) {
            f16x8 wf = *(const f16x8*)(A2T + (16 * wv + lr) * 64 + 32 * ks + 8 * lg);
#pragma unroll
            for (int m = 0; m < 3; ++m) {
                f16x8 bf = *(const f16x8*)(sHA + (16 * m + lr) * 72 + 32 * ks + 8 * lg);
                acc[m] = MFMA16(wf, bf, acc[m]);
            }
        }
#pragma unroll
        for (int m = 0; m < 3; ++m)   // z_E (raw, no elu) -> buf0 cols 144..175
            store4(sB0 + (16 * m + lr) * 200 + 144 + 16 * wv + 4 * lg, acc[m]);
    }
    if (stg) {   // frame 0 -> buf0 cols 8..103
        float tv[24];
#pragma unroll
        for (int i = 0; i < 24; ++i) tv[i] = *(const float*)(xc + a_off[i]);
        f16* dst = sB0 + srow * 200 + 8 + cb;
#pragma unroll
        for (int k = 0; k < 12; ++k) *(unsigned*)(dst + 2 * k) = pk(tv[2 * k], tv[2 * k + 1]);
#pragma unroll
        for (int i = 0; i < 24; ++i) a_off[i] += (lowc && i < 9) ? 12u : 116u;
    }
    __syncthreads();

    // ---- gate hidden: gh = elu(z_E @ gate_W1 + gate_b1) [48x64], K=32 ----
    {
        f32x4 bi = *(const f32x4*)(gb1 + 16 * wv + 4 * lg);
        f32x4 acc[3];
#pragma unroll
        for (int m = 0; m < 3; ++m) acc[m] = bi;
        f16x8 wf = *(const f16x8*)(G1T + (16 * wv + lr) * 32 + 8 * lg);
#pragma unroll
        for (int m = 0; m < 3; ++m) {
            f16x8 bf = *(const f16x8*)(sB0 + (16 * m + lr) * 200 + 144 + 8 * lg);
            acc[m] = MFMA16(wf, bf, acc[m]);
        }
#pragma unroll
        for (int m = 0; m < 3; ++m)
            elu_store4(sHA + (16 * m + lr) * 72 + 16 * wv + 4 * lg, acc[m]);
    }
    __syncthreads();

    // ---- gate logits (wave 0): gl = gh @ gate_W2 + gate_b2 -> sWf ----
    // Guard: lg==0 writes cols 0..3; lg==1 writes col 4 only (R2/R3 OOB lesson).
    if (wv == 0) {
        f32x4 bi = *(const f32x4*)(GB2P + 4 * lg);
        f32x4 acc[3];
#pragma unroll
        for (int m = 0; m < 3; ++m) acc[m] = bi;
#pragma unroll
        for (int ks = 0; ks < 2; ++ks) {
            f16x8 wf = *(const f16x8*)(G2T + lr * 64 + 32 * ks + 8 * lg);
#pragma unroll
            for (int m = 0; m < 3; ++m) {
                f16x8 bf = *(const f16x8*)(sHA + (16 * m + lr) * 72 + 32 * ks + 8 * lg);
                acc[m] = MFMA16(wf, bf, acc[m]);
            }
        }
        if (lg == 0) {
#pragma unroll
            for (int m = 0; m < 3; ++m)
                *(f32x4*)(sWf + (16 * m + lr) * 8) = acc[m];
        } else if (lg == 1) {
#pragma unroll
            for (int m = 0; m < 3; ++m)
                sWf[(16 * m + lr) * 8 + 4] = acc[m][0];
        }
    }
    __syncthreads();

    // ---- G1: h = elu(hist @ vae_W1 + vae_b1) [48 x 256], K=480 (5 frames) ----
    f32x4 acc1[3][4];
#pragma unroll
    for (int nt = 0; nt < 4; ++nt) {
        f32x4 bi = *(const f32x4*)(vb1 + 64 * wv + 16 * nt + 4 * lg);
#pragma unroll
        for (int m = 0; m < 3; ++m) acc1[m][nt] = bi;
    }
    for (int f = 0; f < 5; ++f) {
        if (f == 0 && tid < 48) {     // softmax over 5 gate logits
            float g[5];
#pragma unroll
            for (int e = 0; e < 5; ++e) g[e] = sWf[tid * 8 + e];
            float mx = fmaxf(fmaxf(fmaxf(g[0], g[1]), fmaxf(g[2], g[3])), g[4]);
            float s = 0.f;
#pragma unroll
            for (int e = 0; e < 5; ++e) { g[e] = __expf(g[e] - mx); s += g[e]; }
            float inv = 1.f / s;
#pragma unroll
            for (int e = 0; e < 5; ++e) sWf[tid * 8 + e] = g[e] * inv;
        }
        float tv[24];
        if (f < 4 && stg) {
#pragma unroll
            for (int i = 0; i < 24; ++i) tv[i] = *(const float*)(xc + a_off[i]);
        }
        const f16* Bp = (f & 1) ? sB1 : sB0;
        const int bst = (f & 1) ? 104 : 200;
#pragma unroll
        for (int ks = 0; ks < 3; ++ks) {
            f16x8 wf[4];
#pragma unroll
            for (int nt = 0; nt < 4; ++nt)
                wf[nt] = *(const f16x8*)(W1T + (64 * wv + 16 * nt + lr) * 480 + 96 * f + 32 * ks + 8 * lg);
#pragma unroll
            for (int m = 0; m < 3; ++m) {
                f16x8 bf = *(const f16x8*)(Bp + (16 * m + lr) * bst + 8 + 32 * ks + 8 * lg);
#pragma unroll
                for (int nt = 0; nt < 4; ++nt)
                    acc1[m][nt] = MFMA16(wf[nt], bf, acc1[m][nt]);
            }
        }
        if (f < 4 && stg) {           // drain frame f+1 into the other buffer
            f16* dst = (((f + 1) & 1) ? sB1 : sB0) + srow * (((f + 1) & 1) ? 104 : 200) + 8 + cb;
#pragma unroll
            for (int k = 0; k < 12; ++k) *(unsigned*)(dst + 2 * k) = pk(tv[2 * k], tv[2 * k + 1]);
#pragma unroll
            for (int i = 0; i < 24; ++i) a_off[i] += (lowc && i < 9) ? 12u : 116u;
        }
        if (f == 4) {                 // write h (elu) -> sH
#pragma unroll
            for (int m = 0; m < 3; ++m)
#pragma unroll
                for (int nt = 0; nt < 4; ++nt)
                    elu_store4(sH + (16 * m + lr) * 264 + 64 * wv + 16 * nt + 4 * lg, acc1[m][nt]);
        }
        __syncthreads();
    }

    // ---- G2: [v_pred|z_H] = h @ Wzv + bzv, K=256, waves 0..2 -> buf0 ----
    if (wv < 3) {
        f32x4 bz = *(const f32x4*)(BZV + 16 * wv + 4 * lg);
        f32x4 acc[3];
#pragma unroll
        for (int m = 0; m < 3; ++m) acc[m] = bz;
#pragma unroll
        for (int ks = 0; ks < 8; ++ks) {
            f16x8 wf = *(const f16x8*)(WZV + (16 * wv + lr) * 256 + 32 * ks + 8 * lg);
#pragma unroll
            for (int m = 0; m < 3; ++m) {
                f16x8 bf = *(const f16x8*)(sH + (16 * m + lr) * 264 + 32 * ks + 8 * lg);
                acc[m] = MFMA16(wf, bf, acc[m]);
            }
        }
        int j0 = 16 * wv + 4 * lg;
        if (wv < 2 || lg == 0) {
            int col = (wv < 2) ? (108 + j0) : 104;   // z_H at 108.., v_pred at 104..107
#pragma unroll
            for (int m = 0; m < 3; ++m)
                store4(sB0 + (16 * m + lr) * 200 + col, acc[m]);
        }
    }
    __syncthreads();

    // ---- experts: 5 x (L1 K=192, L2 K=128, L3 K=128) ----
    f32x4 oacc[2];
    oacc[0] = (f32x4)0.f; oacc[1] = (f32x4)0.f;

    for (int e = 0; e < 5; ++e) {
        // L1: h1 = elu(inp @ eW1 + eb1): 32 cols/wave
        {
            f32x4 acc[3][2];
#pragma unroll
            for (int nt = 0; nt < 2; ++nt) {
                f32x4 bi = *(const f32x4*)(eb1 + e * 128 + 32 * wv + 16 * nt + 4 * lg);
#pragma unroll
                for (int m = 0; m < 3; ++m) acc[m][nt] = bi;
            }
#pragma unroll
            for (int ks = 0; ks < 6; ++ks) {
                f16x8 wf[2];
#pragma unroll
                for (int nt = 0; nt < 2; ++nt)
                    wf[nt] = *(const f16x8*)(E1T + (e * 128 + 32 * wv + 16 * nt + lr) * 192 + 32 * ks + 8 * lg);
#pragma unroll
                for (int m = 0; m < 3; ++m) {
                    f16x8 bf = *(const f16x8*)(sB0 + (16 * m + lr) * 200 + 32 * ks + 8 * lg);
#pragma unroll
                    for (int nt = 0; nt < 2; ++nt) acc[m][nt] = MFMA16(wf[nt], bf, acc[m][nt]);
                }
            }
#pragma unroll
            for (int m = 0; m < 3; ++m)
#pragma unroll
                for (int nt = 0; nt < 2; ++nt)
                    elu_store4(sH1 + (16 * m + lr) * 136 + 32 * wv + 16 * nt + 4 * lg, acc[m][nt]);
        }
        __syncthreads();
        // L2: h2 = elu(h1 @ eW2 + eb2)
        {
            f32x4 acc[3][2];
#pragma unroll
            for (int nt = 0; nt < 2; ++nt) {
                f32x4 bi = *(const f32x4*)(eb2 + e * 128 + 32 * wv + 16 * nt + 4 * lg);
#pragma unroll
                for (int m = 0; m < 3; ++m) acc[m][nt] = bi;
            }
#pragma unroll
            for (int ks = 0; ks < 4; ++ks) {
                f16x8 wf[2];
#pragma unroll
                for (int nt = 0; nt < 2; ++nt)
                    wf[nt] = *(const f16x8*)(E2T + (e * 128 + 32 * wv + 16 * nt + lr) * 128 + 32 * ks + 8 * lg);
#pragma unroll
                for (int m = 0; m < 3; ++m) {
                    f16x8 bf = *(const f16x8*)(sH1 + (16 * m + lr) * 136 + 32 * ks + 8 * lg);
#pragma unroll
                    for (int nt = 0; nt < 2; ++nt) acc[m][nt] = MFMA16(wf[nt], bf, acc[m][nt]);
                }
            }
#pragma unroll
            for (int m = 0; m < 3; ++m)
#pragma unroll
                for (int nt = 0; nt < 2; ++nt)
                    elu_store4(sH2 + (16 * m + lr) * 136 + 32 * wv + 16 * nt + 4 * lg, acc[m][nt]);
        }
        __syncthreads();
        // L3: acts = h2 @ eW3 + eb3 ; weight and accumulate. waves 0..2 (rows 16wv..)
        if (wv < 3) {
            f32x4 acc3[2];
#pragma unroll
            for (int nt = 0; nt < 2; ++nt)
                acc3[nt] = *(const f32x4*)(EB3P + e * 32 + 16 * nt + 4 * lg);
#pragma unroll
            for (int ks = 0; ks < 4; ++ks) {
                f16x8 bf = *(const f16x8*)(sH2 + (16 * wv + lr) * 136 + 32 * ks + 8 * lg);
#pragma unroll
                for (int nt = 0; nt < 2; ++nt) {
                    f16x8 wf = *(const f16x8*)(E3T + (e * 32 + 16 * nt + lr) * 128 + 32 * ks + 8 * lg);
                    acc3[nt] = MFMA16(wf, bf, acc3[nt]);
                }
            }
            float we = sWf[(16 * wv + lr) * 8 + e];
#pragma unroll
            for (int nt = 0; nt < 2; ++nt)
#pragma unroll
                for (int r = 0; r < 4; ++r) oacc[nt][r] += we * acc3[nt][r];
        }
        __syncthreads();
    }

    // ---- store out [48 x 29] fp32: waves 0..2, lane holds row (16wv+lr) ----
    if (wv < 3) {
        int row = row0 + 16 * wv + lr;
        if (row < n) {
#pragma unroll
            for (int nt = 0; nt < 2; ++nt)
#pragma unroll
                for (int r = 0; r < 4; ++r) {
                    int col = 16 * nt + 4 * lg + r;
                    if (col < 29) out[(size_t)row * 29 + col] = oacc[nt][r];
                }
        }
    }
}

extern "C" void kernel_launch(void* const* d_in, const int* in_sizes, int n_in,
                              void* d_out, int out_size, void* d_ws, size_t ws_size,
                              hipStream_t stream)
{
    (void)n_in; (void)out_size; (void)ws_size;
    const float* x   = (const float*)d_in[0];
    const float* vW1 = (const float*)d_in[1];
    const float* vb1 = (const float*)d_in[2];
    const float* vWz = (const float*)d_in[3];
    const float* vbz = (const float*)d_in[4];
    const float* vWv = (const float*)d_in[5];
    const float* vbv = (const float*)d_in[6];
    const float* aW1 = (const float*)d_in[7];
    const float* ab1 = (const float*)d_in[8];
    const float* aW2 = (const float*)d_in[9];
    const float* ab2 = (const float*)d_in[10];
    const float* gW1 = (const float*)d_in[11];
    const float* gb1 = (const float*)d_in[12];
    const float* gW2 = (const float*)d_in[13];
    const float* gb2 = (const float*)d_in[14];
    const float* eW1 = (const float*)d_in[15];
    const float* eb1 = (const float*)d_in[16];
    const float* eW2 = (const float*)d_in[17];
    const float* eb2 = (const float*)d_in[18];
    const float* eW3 = (const float*)d_in[19];
    const float* eb3 = (const float*)d_in[20];

    int n = in_sizes[0] / 975;

    prep_kernel<<<(371936 + 255) / 256, 256, 0, stream>>>(
        vW1, vWz, vWv, aW1, aW2, gW1, gW2, eW1, eW2, eW3, vbz, vbv, eb3, gb2, (char*)d_ws);

    moe_fused<<<(n + 47) / 48, 256, 0, stream>>>(
        x, vb1, ab1, ab2, gb1, eb1, eb2, (const char*)d_ws, (float*)d_out, n);
}

// Round 6
// 329.884 us; speedup vs baseline: 1.0549x; 1.0549x over previous
//
#include <hip/hip_runtime.h>
#include <math.h>

typedef _Float16 f16;
typedef f16  f16x8 __attribute__((ext_vector_type(8)));
typedef float f32x4 __attribute__((ext_vector_type(4)));
typedef unsigned short ushort_t;

#define MFMA16(a, b, c) __builtin_amdgcn_mfma_f32_16x16x32_f16((a), (b), (c), 0, 0, 0)

// ---------------- workspace layout (f16 element offsets) ----------------
#define W1T_E 0        // [256][512]  vae_W1^T, K permuted to S2 order (zeros at 0..2, 483..511)
#define WZV_E 131072   // [48][256]   [vae_Wz | vae_Wv | 0]^T
#define A1T_E 143360   // [64][96]    ae_W1^T
#define A2T_E 149504   // [32][64]    ae_W2^T
#define G1T_E 151552   // [64][32]    gate_W1^T
#define G2T_E 153600   // [16][64]    gate_W2^T (cols 5..15 zero)
#define E1T_E 154624   // [5][128][192] eW1^T, K remapped to padded-192 buf0 layout
#define E2T_E 277504   // [5][128][128] eW2^T
#define E3T_E 359424   // [5][32][128]  eW3^T, cols 29..31 zero
#define F32_B 759808   // byte offset of f32 appendix:
                       //   [0..47]   BZV  = [vae_bz | vae_bv | 0]
                       //   [48..207] EB3P = eb3 padded [5][32]
                       //   [208..223]GB2P = gate_b2 padded [16]

// ---------------- LDS layout (bytes), 64-row tile, 2 blocks/CU ----------------
// S2 region [64][488] f16: row-image of x cols 12..495 (S2[0..2]=term0 f4,
//   S2[3..482]=x[15..494] natural order, S2[483]=x[495] dead, 484..487 zero).
//   G1 reads K-window 0..511 (row-overlap reads covered by zero weights).
// After G1: h [64][264] at 0, buf0 [64][200] at 36864 (both inside S2 region).
// Experts: H1 [64][136] at 0, H2 at 17408 (h dead after G2).
// ELEV region [64][104] f16 at 62528; after G3: ha/gh [64][72] at 62528,
//   zE [64][32] at 71744 (exactly fills elev region).
#define S2_OFF   0
#define B0_OFF   36864
#define H2_OFF   17408
#define ELEV_OFF 62528
#define HA_OFF   62528
#define ZE_OFF   71744
#define WF_OFF   75840  // [64][8] f32 gate weights
#define SMEM_SZ  77888  // 2 x 77888 <= 163840 -> 2 blocks/CU

__device__ __forceinline__ float elu_f(float v) {
    float e = __expf(v) - 1.f;
    return v > 0.f ? v : e;
}

// round-to-nearest f32x2 -> packed f16x2 (RTZ pkrtz biased the chain; keep RTN)
__device__ __forceinline__ unsigned pk(float a, float b) {
    ushort_t u0 = __builtin_bit_cast(ushort_t, (f16)a);
    ushort_t u1 = __builtin_bit_cast(ushort_t, (f16)b);
    return (unsigned)u0 | ((unsigned)u1 << 16);
}

__device__ __forceinline__ void store4(f16* p, f32x4 v) {
    uint2 t; t.x = pk(v[0], v[1]); t.y = pk(v[2], v[3]);
    *(uint2*)p = t;
}

__device__ __forceinline__ void elu_store4(f16* p, f32x4 v) {
    uint2 t; t.x = pk(elu_f(v[0]), elu_f(v[1])); t.y = pk(elu_f(v[2]), elu_f(v[3]));
    *(uint2*)p = t;
}

// ---------------- weight repack: fp32 -> f16, transposed/padded/permuted ----------------
__global__ void prep_kernel(const float* __restrict__ vW1, const float* __restrict__ vWz,
                            const float* __restrict__ vWv, const float* __restrict__ aW1,
                            const float* __restrict__ aW2, const float* __restrict__ gW1,
                            const float* __restrict__ gW2, const float* __restrict__ eW1,
                            const float* __restrict__ eW2, const float* __restrict__ eW3,
                            const float* __restrict__ vbz, const float* __restrict__ vbv,
                            const float* __restrict__ eb3, const float* __restrict__ gb2,
                            char* __restrict__ ws)
{
    int i = blockIdx.x * 256 + threadIdx.x;
    f16* H = (f16*)ws;
    if (i < 131072) {                                   // W1T [c=256][ks=512], S2-order K
        int c = i >> 9, ks = i & 511;
        int xcol = 12 + ks;
        float v = 0.f;
        if (xcol >= 15 && xcol <= 494) {
            int hc;
            if (xcol < 60) {                            // terms 1-3 (d=3)
                int t = xcol / 15; int rm = xcol - 15 * t; int f = rm / 3;
                hc = 96 * f + 3 * (t - 1) + (rm - 3 * f);
            } else {                                    // terms 4-6 (d=29)
                int t2 = (xcol - 60) / 145; int rm = xcol - 60 - 145 * t2; int f = rm / 29;
                hc = 96 * f + 9 + 29 * t2 + (rm - 29 * f);
            }
            v = vW1[hc * 256 + c];
        }
        H[i] = (f16)v;
    } else if (i < 143360) {                            // WZV [c=48][k=256]
        int j = i - 131072; int c = j / 256, k = j - c * 256;
        float v = (c < 32) ? vWz[k * 32 + c] : ((c < 35) ? vWv[k * 3 + (c - 32)] : 0.f);
        H[i] = (f16)v;
    } else if (i < 149504) {                            // A1T [c=64][k=96]
        int j = i - 143360; int c = j / 96, k = j - c * 96;
        H[i] = (f16)aW1[k * 64 + c];
    } else if (i < 151552) {                            // A2T [c=32][k=64]
        int j = i - 149504; int c = j / 64, k = j - c * 64;
        H[i] = (f16)aW2[k * 32 + c];
    } else if (i < 153600) {                            // G1T [c=64][k=32]
        int j = i - 151552; int c = j / 32, k = j - c * 32;
        H[i] = (f16)gW1[k * 64 + c];
    } else if (i < 154624) {                            // G2T [c=16][k=64]
        int j = i - 153600; int c = j / 64, k = j - c * 64;
        H[i] = (f16)((c < 5) ? gW2[k * 5 + c] : 0.f);
    } else if (i < 277504) {                            // E1T [e][c=128][k=192] remapped
        int j = i - 154624; int e = j / 24576, jj = j - e * 24576;
        int c = jj / 192, k = jj - c * 192;
        int ko = (k >= 5 && k < 107)   ? (k - 5)
               : (k >= 108 && k < 140) ? (k - 6)
               : (k >= 144 && k < 176) ? (k - 10) : -1;
        H[i] = (f16)((ko >= 0) ? eW1[(e * 166 + ko) * 128 + c] : 0.f);
    } else if (i < 359424) {                            // E2T [e][c=128][k=128]
        int j = i - 277504; int e = j / 16384, jj = j - e * 16384;
        int c = jj / 128, k = jj - c * 128;
        H[i] = (f16)eW2[(e * 128 + k) * 128 + c];
    } else if (i < 379904) {                            // E3T [e][c=32][k=128]
        int j = i - 359424; int e = j / 4096, jj = j - e * 4096;
        int c = jj / 128, k = jj - c * 128;
        H[i] = (f16)((c < 29) ? eW3[(e * 128 + k) * 29 + c] : 0.f);
    } else if (i < 380128) {                            // f32 appendix
        int j = i - 379904;
        float* F = (float*)(ws + F32_B);
        float v;
        if (j < 48)       v = (j < 32) ? vbz[j] : ((j < 35) ? vbv[j - 32] : 0.f);
        else if (j < 208) { int t = j - 48; int e = t >> 5, c = t & 31;
                            v = (c < 29) ? eb3[e * 29 + c] : 0.f; }
        else              { int t = j - 208; v = (t < 5) ? gb2[t] : 0.f; }
        F[j] = v;
    }
}

// ---------------- fused actor, 64 rows/block, coalesced staging ----------------
__global__ __launch_bounds__(256, 2) void moe_fused(
    const float* __restrict__ x,
    const float* __restrict__ vb1,
    const float* __restrict__ ab1,
    const float* __restrict__ ab2,
    const float* __restrict__ gb1,
    const float* __restrict__ eb1,
    const float* __restrict__ eb2,
    const char* __restrict__ ws,
    float* __restrict__ out)
{
    __shared__ __align__(16) char smem[SMEM_SZ];
    const int tid  = threadIdx.x;
    const int wv   = tid >> 6;
    const int lane = tid & 63;
    const int lr   = lane & 15;
    const int lg   = lane >> 4;
    const int row0 = (int)blockIdx.x * 64;

    const f16* W1T = (const f16*)ws + W1T_E;
    const f16* WZV = (const f16*)ws + WZV_E;
    const f16* A1T = (const f16*)ws + A1T_E;
    const f16* A2T = (const f16*)ws + A2T_E;
    const f16* G1T = (const f16*)ws + G1T_E;
    const f16* G2T = (const f16*)ws + G2T_E;
    const f16* E1T = (const f16*)ws + E1T_E;
    const f16* E2T = (const f16*)ws + E2T_E;
    const f16* E3T = (const f16*)ws + E3T_E;
    const float* BZV  = (const float*)(ws + F32_B);
    const float* EB3P = BZV + 48;
    const float* GB2P = BZV + 208;

    f16* sS2 = (f16*)(smem + S2_OFF);     // stride 488
    f16* sEl = (f16*)(smem + ELEV_OFF);   // stride 104
    f16* sHA = (f16*)(smem + HA_OFF);     // stride 72 (ha, then gh)
    f16* sZE = (f16*)(smem + ZE_OFF);     // stride 32
    f16* sH  = (f16*)(smem + S2_OFF);     // stride 264 (after G1)
    f16* sB0 = (f16*)(smem + B0_OFF);     // stride 200 (after G1)
    f16* sH1 = (f16*)(smem + S2_OFF);     // stride 136 (experts)
    f16* sH2 = (f16*)(smem + H2_OFF);     // stride 136
    float* sWf = (float*)(smem + WF_OFF); // stride 8 f32

    // ---- P0: coalesced staging of S2 + elev (lanes cover consecutive floats) ----
    {
        if (tid < 16) *(unsigned*)(smem + 62464 + 4 * tid) = 0u;  // S2 tail pad
        const int sr0 = wv * 16;
        for (int rr = 0; rr < 16; ++rr) {
            const int r = sr0 + rr;
            const float* xr = x + (size_t)(row0 + r) * 975;
            if (lane < 48) {              // elevation: 96 floats -> 48 pairs
                float a = xr[879 + 2 * lane], b = xr[880 + 2 * lane];
                *(unsigned*)(sEl + r * 104 + 2 * lane) = pk(a, b);
            }
            f16* dst = sS2 + r * 488;
#pragma unroll
            for (int j = 0; j < 4; ++j) {
                int p = j * 64 + lane;    // pair index within row
                if (p < 244) {
                    float a = 0.f, b = 0.f;
                    if (p < 242) { a = xr[12 + 2 * p]; b = xr[13 + 2 * p]; }
                    *(unsigned*)(dst + 2 * p) = pk(a, b);  // pairs 242,243 = zeros
                }
            }
        }
    }
    __syncthreads();

    // ---- G3: ha = elu(e_t @ ae_W1 + ae_b1) [64x64], K=96 (acc regs; write after bar) ----
    f32x4 g3acc[4];
    {
        f32x4 bi = *(const f32x4*)(ab1 + 16 * wv + 4 * lg);
#pragma unroll
        for (int m = 0; m < 4; ++m) g3acc[m] = bi;
#pragma unroll
        for (int ks = 0; ks < 3; ++ks) {
            f16x8 wf = *(const f16x8*)(A1T + (16 * wv + lr) * 96 + 32 * ks + 8 * lg);
#pragma unroll
            for (int m = 0; m < 4; ++m) {
                f16x8 bf = *(const f16x8*)(sEl + (16 * m + lr) * 104 + 32 * ks + 8 * lg);
                g3acc[m] = MFMA16(wf, bf, g3acc[m]);
            }
        }
    }
    __syncthreads();   // elev reads complete before ha overwrites the region
#pragma unroll
    for (int m = 0; m < 4; ++m)
        elu_store4(sHA + (16 * m + lr) * 72 + 16 * wv + 4 * lg, g3acc[m]);
    __syncthreads();

    // ---- G4 (waves 0,1): z_E = ha @ ae_W2 + ae_b2 -> sZE ----
    if (wv < 2) {
        f32x4 bi = *(const f32x4*)(ab2 + 16 * wv + 4 * lg);
        f32x4 acc[4];
#pragma unroll
        for (int m = 0; m < 4; ++m) acc[m] = bi;
#pragma unroll
        for (int ks = 0; ks < 2; ++ks) {
            f16x8 wf = *(const f16x8*)(A2T + (16 * wv + lr) * 64 + 32 * ks + 8 * lg);
#pragma unroll
            for (int m = 0; m < 4; ++m) {
                f16x8 bf = *(const f16x8*)(sHA + (16 * m + lr) * 72 + 32 * ks + 8 * lg);
                acc[m] = MFMA16(wf, bf, acc[m]);
            }
        }
#pragma unroll
        for (int m = 0; m < 4; ++m)
            store4(sZE + (16 * m + lr) * 32 + 16 * wv + 4 * lg, acc[m]);
    }
    __syncthreads();

    // ---- gate hidden: gh = elu(z_E @ gate_W1 + gate_b1), K=32 -> sHA (ha dead) ----
    {
        f32x4 bi = *(const f32x4*)(gb1 + 16 * wv + 4 * lg);
        f32x4 acc[4];
#pragma unroll
        for (int m = 0; m < 4; ++m) acc[m] = bi;
        f16x8 wf = *(const f16x8*)(G1T + (16 * wv + lr) * 32 + 8 * lg);
#pragma unroll
        for (int m = 0; m < 4; ++m) {
            f16x8 bf = *(const f16x8*)(sZE + (16 * m + lr) * 32 + 8 * lg);
            acc[m] = MFMA16(wf, bf, acc[m]);
        }
#pragma unroll
        for (int m = 0; m < 4; ++m)
            elu_store4(sHA + (16 * m + lr) * 72 + 16 * wv + 4 * lg, acc[m]);
    }
    __syncthreads();

    // ---- gate logits (wave 0) -> sWf ; guarded (R2/R3 OOB lesson) ----
    if (wv == 0) {
        f32x4 bi = *(const f32x4*)(GB2P + 4 * lg);
        f32x4 acc[4];
#pragma unroll
        for (int m = 0; m < 4; ++m) acc[m] = bi;
#pragma unroll
        for (int ks = 0; ks < 2; ++ks) {
            f16x8 wf = *(const f16x8*)(G2T + lr * 64 + 32 * ks + 8 * lg);
#pragma unroll
            for (int m = 0; m < 4; ++m) {
                f16x8 bf = *(const f16x8*)(sHA + (16 * m + lr) * 72 + 32 * ks + 8 * lg);
                acc[m] = MFMA16(wf, bf, acc[m]);
            }
        }
        if (lg == 0) {
#pragma unroll
            for (int m = 0; m < 4; ++m)
                *(f32x4*)(sWf + (16 * m + lr) * 8) = acc[m];
        } else if (lg == 1) {
#pragma unroll
            for (int m = 0; m < 4; ++m)
                sWf[(16 * m + lr) * 8 + 4] = acc[m][0];
        }
    }
    __syncthreads();

    // ---- softmax over 5 gate logits (rows = tid<64) ----
    if (tid < 64) {
        float g[5];
#pragma unroll
        for (int e = 0; e < 5; ++e) g[e] = sWf[tid * 8 + e];
        float mx = fmaxf(fmaxf(fmaxf(g[0], g[1]), fmaxf(g[2], g[3])), g[4]);
        float s = 0.f;
#pragma unroll
        for (int e = 0; e < 5; ++e) { g[e] = __expf(g[e] - mx); s += g[e]; }
        float inv = 1.f / s;
#pragma unroll
        for (int e = 0; e < 5; ++e) sWf[tid * 8 + e] = g[e] * inv;
    }

    // ---- G1: h = elu(hist @ vae_W1 + vae_b1) [64x256], K=512 window over S2 ----
    f32x4 acc1[4][4];
#pragma unroll
    for (int nt = 0; nt < 4; ++nt) {
        f32x4 bi = *(const f32x4*)(vb1 + 64 * wv + 16 * nt + 4 * lg);
#pragma unroll
        for (int m = 0; m < 4; ++m) acc1[m][nt] = bi;
    }
#pragma unroll
    for (int ks = 0; ks < 16; ++ks) {
        f16x8 wf[4];
#pragma unroll
        for (int nt = 0; nt < 4; ++nt)
            wf[nt] = *(const f16x8*)(W1T + (64 * wv + 16 * nt + lr) * 512 + 32 * ks + 8 * lg);
#pragma unroll
        for (int m = 0; m < 4; ++m) {
            f16x8 bf = *(const f16x8*)(sS2 + (16 * m + lr) * 488 + 32 * ks + 8 * lg);
#pragma unroll
            for (int nt = 0; nt < 4; ++nt)
                acc1[m][nt] = MFMA16(wf[nt], bf, acc1[m][nt]);
        }
    }
    // prefetch o_t (99 cols of S2) into regs before S2 is overwritten
    const int r_ot = tid >> 2, sub = tid & 3;
    ushort_t otv[25];
#pragma unroll
    for (int i = 0; i < 25; ++i) {
        int j = sub + 4 * i;
        if (j < 99) {
            int s;
            if (j < 3) s = j;                                        // term0 f4
            else if (j < 12) { int jj = j - 3; int t = jj / 3;       // terms1-3 f4
                               s = 15 * (t + 1) + (jj - 3 * t); }
            else { int jj = j - 12; int t2 = jj / 29;                // terms4-6 f4
                   s = 164 + 145 * t2 + (jj - 29 * t2); }
            otv[i] = __builtin_bit_cast(ushort_t, sS2[r_ot * 488 + s]);
        }
    }
    __syncthreads();   // all S2 reads done; region becomes h + buf0

    // write h (elu)
#pragma unroll
    for (int m = 0; m < 4; ++m)
#pragma unroll
        for (int nt = 0; nt < 4; ++nt)
            elu_store4(sH + (16 * m + lr) * 264 + 64 * wv + 16 * nt + 4 * lg, acc1[m][nt]);
    // assemble buf0: o_t (cols 5..103), zeros, z_E copy
#pragma unroll
    for (int i = 0; i < 25; ++i) {
        int j = sub + 4 * i;
        if (j < 99) sB0[r_ot * 200 + 5 + j] = __builtin_bit_cast(f16, otv[i]);
    }
    {
        char* b0r = (char*)sB0 + r_ot * 400;
        if (sub == 0) { *(uint2*)(b0r + 0) = (uint2){0u, 0u}; *(ushort_t*)(b0r + 8) = 0; } // cols 0..4
        else if (sub == 1) { *(uint2*)(b0r + 280) = (uint2){0u, 0u}; }                      // cols 140..143
        else if (sub == 2) { *(uint4*)(b0r + 352) = (uint4){0u,0u,0u,0u}; }                 // cols 176..183
        else               { *(uint4*)(b0r + 368) = (uint4){0u,0u,0u,0u}; }                 // cols 184..191
    }
#pragma unroll
    for (int it = 0; it < 2; ++it) {   // z_E -> buf0 cols 144..175 (b64 copies)
        int idx = tid + 256 * it;      // 512 quads
        int r = idx >> 3, c4 = idx & 7;
        uint2 v = *(uint2*)((char*)sZE + r * 64 + 8 * c4);
        *(uint2*)((char*)sB0 + r * 400 + 288 + 8 * c4) = v;
    }
    __syncthreads();

    // ---- G2: [v_pred|z_H] = h @ Wzv + bzv, K=256, waves 0..2 -> buf0 ----
    if (wv < 3) {
        f32x4 bz = *(const f32x4*)(BZV + 16 * wv + 4 * lg);
        f32x4 acc[4];
#pragma unroll
        for (int m = 0; m < 4; ++m) acc[m] = bz;
#pragma unroll
        for (int ks = 0; ks < 8; ++ks) {
            f16x8 wf = *(const f16x8*)(WZV + (16 * wv + lr) * 256 + 32 * ks + 8 * lg);
#pragma unroll
            for (int m = 0; m < 4; ++m) {
                f16x8 bf = *(const f16x8*)(sH + (16 * m + lr) * 264 + 32 * ks + 8 * lg);
                acc[m] = MFMA16(wf, bf, acc[m]);
            }
        }
        int j0 = 16 * wv + 4 * lg;
        if (wv < 2 || lg == 0) {
            int col = (wv < 2) ? (108 + j0) : 104;   // z_H at 108.., v_pred at 104..107
#pragma unroll
            for (int m = 0; m < 4; ++m)
                store4(sB0 + (16 * m + lr) * 200 + col, acc[m]);
        }
    }
    __syncthreads();

    // ---- experts: 5 x (L1 K=192, L2 K=128, L3 K=128) ----
    f32x4 oacc[2];
    oacc[0] = (f32x4)0.f; oacc[1] = (f32x4)0.f;

    for (int e = 0; e < 5; ++e) {
        // L1: h1 = elu(inp @ eW1 + eb1): 32 cols/wave (writes H1, h dead)
        {
            f32x4 acc[4][2];
#pragma unroll
            for (int nt = 0; nt < 2; ++nt) {
                f32x4 bi = *(const f32x4*)(eb1 + e * 128 + 32 * wv + 16 * nt + 4 * lg);
#pragma unroll
                for (int m = 0; m < 4; ++m) acc[m][nt] = bi;
            }
#pragma unroll
            for (int ks = 0; ks < 6; ++ks) {
                f16x8 wf[2];
#pragma unroll
                for (int nt = 0; nt < 2; ++nt)
                    wf[nt] = *(const f16x8*)(E1T + (e * 128 + 32 * wv + 16 * nt + lr) * 192 + 32 * ks + 8 * lg);
#pragma unroll
                for (int m = 0; m < 4; ++m) {
                    f16x8 bf = *(const f16x8*)(sB0 + (16 * m + lr) * 200 + 32 * ks + 8 * lg);
#pragma unroll
                    for (int nt = 0; nt < 2; ++nt) acc[m][nt] = MFMA16(wf[nt], bf, acc[m][nt]);
                }
            }
#pragma unroll
            for (int m = 0; m < 4; ++m)
#pragma unroll
                for (int nt = 0; nt < 2; ++nt)
                    elu_store4(sH1 + (16 * m + lr) * 136 + 32 * wv + 16 * nt + 4 * lg, acc[m][nt]);
        }
        __syncthreads();
        // L2: h2 = elu(h1 @ eW2 + eb2)
        {
            f32x4 acc[4][2];
#pragma unroll
            for (int nt = 0; nt < 2; ++nt) {
                f32x4 bi = *(const f32x4*)(eb2 + e * 128 + 32 * wv + 16 * nt + 4 * lg);
#pragma unroll
                for (int m = 0; m < 4; ++m) acc[m][nt] = bi;
            }
#pragma unroll
            for (int ks = 0; ks < 4; ++ks) {
                f16x8 wf[2];
#pragma unroll
                for (int nt = 0; nt < 2; ++nt)
                    wf[nt] = *(const f16x8*)(E2T + (e * 128 + 32 * wv + 16 * nt + lr) * 128 + 32 * ks + 8 * lg);
#pragma unroll
                for (int m = 0; m < 4; ++m) {
                    f16x8 bf = *(const f16x8*)(sH1 + (16 * m + lr) * 136 + 32 * ks + 8 * lg);
#pragma unroll
                    for (int nt = 0; nt < 2; ++nt) acc[m][nt] = MFMA16(wf[nt], bf, acc[m][nt]);
                }
            }
#pragma unroll
            for (int m = 0; m < 4; ++m)
#pragma unroll
                for (int nt = 0; nt < 2; ++nt)
                    elu_store4(sH2 + (16 * m + lr) * 136 + 32 * wv + 16 * nt + 4 * lg, acc[m][nt]);
        }
        __syncthreads();
        // L3: acts = h2 @ eW3 + eb3 ; weight and accumulate (rows 16wv+lr)
        {
            f32x4 acc3[2];
#pragma unroll
            for (int nt = 0; nt < 2; ++nt)
                acc3[nt] = *(const f32x4*)(EB3P + e * 32 + 16 * nt + 4 * lg);
#pragma unroll
            for (int ks = 0; ks < 4; ++ks) {
                f16x8 bf = *(const f16x8*)(sH2 + (16 * wv + lr) * 136 + 32 * ks + 8 * lg);
#pragma unroll
                for (int nt = 0; nt < 2; ++nt) {
                    f16x8 wf = *(const f16x8*)(E3T + (e * 32 + 16 * nt + lr) * 128 + 32 * ks + 8 * lg);
                    acc3[nt] = MFMA16(wf, bf, acc3[nt]);
                }
            }
            float we = sWf[(16 * wv + lr) * 8 + e];
#pragma unroll
            for (int nt = 0; nt < 2; ++nt)
#pragma unroll
                for (int r = 0; r < 4; ++r) oacc[nt][r] += we * acc3[nt][r];
        }
        __syncthreads();
    }

    // ---- store out [64 x 29] fp32: lane holds row (16wv+lr), 4-col groups ----
    {
        int row = row0 + 16 * wv + lr;
#pragma unroll
        for (int nt = 0; nt < 2; ++nt)
#pragma unroll
            for (int r = 0; r < 4; ++r) {
                int col = 16 * nt + 4 * lg + r;
                if (col < 29) out[(size_t)row * 29 + col] = oacc[nt][r];
            }
    }
}

extern "C" void kernel_launch(void* const* d_in, const int* in_sizes, int n_in,
                              void* d_out, int out_size, void* d_ws, size_t ws_size,
                              hipStream_t stream)
{
    (void)n_in; (void)out_size; (void)ws_size;
    const float* x   = (const float*)d_in[0];
    const float* vW1 = (const float*)d_in[1];
    const float* vb1 = (const float*)d_in[2];
    const float* vWz = (const float*)d_in[3];
    const float* vbz = (const float*)d_in[4];
    const float* vWv = (const float*)d_in[5];
    const float* vbv = (const float*)d_in[6];
    const float* aW1 = (const float*)d_in[7];
    const float* ab1 = (const float*)d_in[8];
    const float* aW2 = (const float*)d_in[9];
    const float* ab2 = (const float*)d_in[10];
    const float* gW1 = (const float*)d_in[11];
    const float* gb1 = (const float*)d_in[12];
    const float* gW2 = (const float*)d_in[13];
    const float* gb2 = (const float*)d_in[14];
    const float* eW1 = (const float*)d_in[15];
    const float* eb1 = (const float*)d_in[16];
    const float* eW2 = (const float*)d_in[17];
    const float* eb2 = (const float*)d_in[18];
    const float* eW3 = (const float*)d_in[19];
    const float* eb3 = (const float*)d_in[20];

    int n = in_sizes[0] / 975;

    prep_kernel<<<(380128 + 255) / 256, 256, 0, stream>>>(
        vW1, vWz, vWv, aW1, aW2, gW1, gW2, eW1, eW2, eW3, vbz, vbv, eb3, gb2, (char*)d_ws);

    moe_fused<<<n / 64, 256, 0, stream>>>(
        x, vb1, ab1, ab2, gb1, eb1, eb2, (const char*)d_ws, (float*)d_out);
}

// Round 7
// 318.392 us; speedup vs baseline: 1.0929x; 1.0361x over previous
//
#include <hip/hip_runtime.h>
#include <math.h>

typedef _Float16 f16;
typedef f16  f16x8 __attribute__((ext_vector_type(8)));
typedef float f32x4 __attribute__((ext_vector_type(4)));
typedef unsigned short ushort_t;

#define MFMA16(a, b, c) __builtin_amdgcn_mfma_f32_16x16x32_f16((a), (b), (c), 0, 0, 0)

// ---------------- workspace layout (f16 element offsets) ----------------
#define W1T_E 0        // [256][512]  vae_W1^T, K permuted to S2 order (zeros at 0..2, 483..511)
#define WZV_E 131072   // [48][256]   [vae_Wz | vae_Wv | 0]^T
#define A1T_E 143360   // [64][96]    ae_W1^T
#define A2T_E 149504   // [32][64]    ae_W2^T
#define G1T_E 151552   // [64][32]    gate_W1^T
#define G2T_E 153600   // [16][64]    gate_W2^T (cols 5..15 zero)
#define E1T_E 154624   // [5][128][192] eW1^T, K remapped to padded-192 buf0 layout
#define E2T_E 277504   // [5][128][128] eW2^T
#define E3T_E 359424   // [5][32][128]  eW3^T, cols 29..31 zero
#define F32_B 759808   // byte offset of f32 appendix:
                       //   [0..47]   BZV  = [vae_bz | vae_bv | 0]
                       //   [48..207] EB3P = eb3 padded [5][32]
                       //   [208..223]GB2P = gate_b2 padded [16]

// ---------------- LDS layout (bytes), 64-row tile, 2 blocks/CU ----------------
#define S2_OFF   0
#define B0_OFF   36864
#define H2_OFF   17408
#define ELEV_OFF 62528
#define HA_OFF   62528
#define ZE_OFF   71744
#define WF_OFF   75840  // [64][8] f32 gate weights
#define SMEM_SZ  77888  // 2 x 77888 <= 163840 -> 2 blocks/CU

__device__ __forceinline__ float elu_f(float v) {
    float e = __expf(v) - 1.f;
    return v > 0.f ? v : e;
}

// round-to-nearest f32x2 -> packed f16x2 (RTZ pkrtz biased the chain; keep RTN)
__device__ __forceinline__ unsigned pk(float a, float b) {
    ushort_t u0 = __builtin_bit_cast(ushort_t, (f16)a);
    ushort_t u1 = __builtin_bit_cast(ushort_t, (f16)b);
    return (unsigned)u0 | ((unsigned)u1 << 16);
}

__device__ __forceinline__ void store4(f16* p, f32x4 v) {
    uint2 t; t.x = pk(v[0], v[1]); t.y = pk(v[2], v[3]);
    *(uint2*)p = t;
}

__device__ __forceinline__ void elu_store4(f16* p, f32x4 v) {
    uint2 t; t.x = pk(elu_f(v[0]), elu_f(v[1])); t.y = pk(elu_f(v[2]), elu_f(v[3]));
    *(uint2*)p = t;
}

// LDS-only barrier: drains DS ops for cross-wave visibility but leaves global
// (weight-prefetch) loads in flight. __syncthreads would drain vmcnt(0) and
// kill the cross-phase pipeline.
__device__ __forceinline__ void sync_lds() {
    asm volatile("s_waitcnt lgkmcnt(0)" ::: "memory");
    __builtin_amdgcn_s_barrier();
    asm volatile("" ::: "memory");
    __builtin_amdgcn_sched_barrier(0);
}

// ---------------- weight repack: fp32 -> f16, transposed/padded/permuted ----------------
__global__ void prep_kernel(const float* __restrict__ vW1, const float* __restrict__ vWz,
                            const float* __restrict__ vWv, const float* __restrict__ aW1,
                            const float* __restrict__ aW2, const float* __restrict__ gW1,
                            const float* __restrict__ gW2, const float* __restrict__ eW1,
                            const float* __restrict__ eW2, const float* __restrict__ eW3,
                            const float* __restrict__ vbz, const float* __restrict__ vbv,
                            const float* __restrict__ eb3, const float* __restrict__ gb2,
                            char* __restrict__ ws)
{
    int i = blockIdx.x * 256 + threadIdx.x;
    f16* H = (f16*)ws;
    if (i < 131072) {                                   // W1T [c=256][ks=512], S2-order K
        int c = i >> 9, ks = i & 511;
        int xcol = 12 + ks;
        float v = 0.f;
        if (xcol >= 15 && xcol <= 494) {
            int hc;
            if (xcol < 60) {
                int t = xcol / 15; int rm = xcol - 15 * t; int f = rm / 3;
                hc = 96 * f + 3 * (t - 1) + (rm - 3 * f);
            } else {
                int t2 = (xcol - 60) / 145; int rm = xcol - 60 - 145 * t2; int f = rm / 29;
                hc = 96 * f + 9 + 29 * t2 + (rm - 29 * f);
            }
            v = vW1[hc * 256 + c];
        }
        H[i] = (f16)v;
    } else if (i < 143360) {                            // WZV [c=48][k=256]
        int j = i - 131072; int c = j / 256, k = j - c * 256;
        float v = (c < 32) ? vWz[k * 32 + c] : ((c < 35) ? vWv[k * 3 + (c - 32)] : 0.f);
        H[i] = (f16)v;
    } else if (i < 149504) {                            // A1T [c=64][k=96]
        int j = i - 143360; int c = j / 96, k = j - c * 96;
        H[i] = (f16)aW1[k * 64 + c];
    } else if (i < 151552) {                            // A2T [c=32][k=64]
        int j = i - 149504; int c = j / 64, k = j - c * 64;
        H[i] = (f16)aW2[k * 32 + c];
    } else if (i < 153600) {                            // G1T [c=64][k=32]
        int j = i - 151552; int c = j / 32, k = j - c * 32;
        H[i] = (f16)gW1[k * 64 + c];
    } else if (i < 154624) {                            // G2T [c=16][k=64]
        int j = i - 153600; int c = j / 64, k = j - c * 64;
        H[i] = (f16)((c < 5) ? gW2[k * 5 + c] : 0.f);
    } else if (i < 277504) {                            // E1T [e][c=128][k=192] remapped
        int j = i - 154624; int e = j / 24576, jj = j - e * 24576;
        int c = jj / 192, k = jj - c * 192;
        int ko = (k >= 5 && k < 107)   ? (k - 5)
               : (k >= 108 && k < 140) ? (k - 6)
               : (k >= 144 && k < 176) ? (k - 10) : -1;
        H[i] = (f16)((ko >= 0) ? eW1[(e * 166 + ko) * 128 + c] : 0.f);
    } else if (i < 359424) {                            // E2T [e][c=128][k=128]
        int j = i - 277504; int e = j / 16384, jj = j - e * 16384;
        int c = jj / 128, k = jj - c * 128;
        H[i] = (f16)eW2[(e * 128 + k) * 128 + c];
    } else if (i < 379904) {                            // E3T [e][c=32][k=128]
        int j = i - 359424; int e = j / 4096, jj = j - e * 4096;
        int c = jj / 128, k = jj - c * 128;
        H[i] = (f16)((c < 29) ? eW3[(e * 128 + k) * 29 + c] : 0.f);
    } else if (i < 380128) {                            // f32 appendix
        int j = i - 379904;
        float* F = (float*)(ws + F32_B);
        float v;
        if (j < 48)       v = (j < 32) ? vbz[j] : ((j < 35) ? vbv[j - 32] : 0.f);
        else if (j < 208) { int t = j - 48; int e = t >> 5, c = t & 31;
                            v = (c < 29) ? eb3[e * 29 + c] : 0.f; }
        else              { int t = j - 208; v = (t < 5) ? gb2[t] : 0.f; }
        F[j] = v;
    }
}

// ---------------- fused actor, 64 rows/block, cross-phase weight prefetch ----------------
__global__ __launch_bounds__(256, 2) void moe_fused(
    const float* __restrict__ x,
    const float* __restrict__ vb1,
    const float* __restrict__ ab1,
    const float* __restrict__ ab2,
    const float* __restrict__ gb1,
    const float* __restrict__ eb1,
    const float* __restrict__ eb2,
    const char* __restrict__ ws,
    float* __restrict__ out)
{
    __shared__ __align__(16) char smem[SMEM_SZ];
    const int tid  = threadIdx.x;
    const int wv   = tid >> 6;
    const int lane = tid & 63;
    const int lr   = lane & 15;
    const int lg   = lane >> 4;
    const int row0 = (int)blockIdx.x * 64;

    const f16* W1T = (const f16*)ws + W1T_E;
    const f16* WZV = (const f16*)ws + WZV_E;
    const f16* A1T = (const f16*)ws + A1T_E;
    const f16* A2T = (const f16*)ws + A2T_E;
    const f16* G1T = (const f16*)ws + G1T_E;
    const f16* G2T = (const f16*)ws + G2T_E;
    const f16* E1T = (const f16*)ws + E1T_E;
    const f16* E2T = (const f16*)ws + E2T_E;
    const f16* E3T = (const f16*)ws + E3T_E;
    const float* BZV  = (const float*)(ws + F32_B);
    const float* EB3P = BZV + 48;
    const float* GB2P = BZV + 208;

    f16* sS2 = (f16*)(smem + S2_OFF);     // stride 488
    f16* sEl = (f16*)(smem + ELEV_OFF);   // stride 104
    f16* sHA = (f16*)(smem + HA_OFF);     // stride 72 (ha, then gh)
    f16* sZE = (f16*)(smem + ZE_OFF);     // stride 32
    f16* sH  = (f16*)(smem + S2_OFF);     // stride 264 (after G1)
    f16* sB0 = (f16*)(smem + B0_OFF);     // stride 200 (after G1)
    f16* sH1 = (f16*)(smem + S2_OFF);     // stride 136 (experts)
    f16* sH2 = (f16*)(smem + H2_OFF);     // stride 136
    float* sWf = (float*)(smem + WF_OFF); // stride 8 f32

    // ---- P0: coalesced staging of S2 + elev ----
    {
        if (tid < 16) *(unsigned*)(smem + 62464 + 4 * tid) = 0u;  // S2 tail pad
        const int sr0 = wv * 16;
        for (int rr = 0; rr < 16; ++rr) {
            const int r = sr0 + rr;
            const float* xr = x + (size_t)(row0 + r) * 975;
            if (lane < 48) {
                float a = xr[879 + 2 * lane], b = xr[880 + 2 * lane];
                *(unsigned*)(sEl + r * 104 + 2 * lane) = pk(a, b);
            }
            f16* dst = sS2 + r * 488;
#pragma unroll
            for (int j = 0; j < 4; ++j) {
                int p = j * 64 + lane;
                if (p < 244) {
                    float a = 0.f, b = 0.f;
                    if (p < 242) { a = xr[12 + 2 * p]; b = xr[13 + 2 * p]; }
                    *(unsigned*)(dst + 2 * p) = pk(a, b);
                }
            }
        }
    }
    // prefetch G3 weights + bias (consumed next phase)
    f16x8 wg3[3]; f32x4 biG3 = *(const f32x4*)(ab1 + 16 * wv + 4 * lg);
#pragma unroll
    for (int ks = 0; ks < 3; ++ks)
        wg3[ks] = *(const f16x8*)(A1T + (16 * wv + lr) * 96 + 32 * ks + 8 * lg);
    sync_lds();                                           // S1

    // ---- G3: ha = elu(e_t @ ae_W1 + ae_b1), K=96 (acc in regs) ----
    f32x4 g3acc[4];
#pragma unroll
    for (int m = 0; m < 4; ++m) g3acc[m] = biG3;
    __builtin_amdgcn_s_setprio(1);
#pragma unroll
    for (int ks = 0; ks < 3; ++ks)
#pragma unroll
        for (int m = 0; m < 4; ++m) {
            f16x8 bf = *(const f16x8*)(sEl + (16 * m + lr) * 104 + 32 * ks + 8 * lg);
            g3acc[m] = MFMA16(wg3[ks], bf, g3acc[m]);
        }
    __builtin_amdgcn_s_setprio(0);
    // prefetch G4 + gate-hidden weights/biases
    f16x8 wg4[2]; f32x4 biG4 = *(const f32x4*)(ab2 + 16 * wv + 4 * lg);
#pragma unroll
    for (int ks = 0; ks < 2; ++ks)
        wg4[ks] = *(const f16x8*)(A2T + (16 * wv + lr) * 64 + 32 * ks + 8 * lg);
    f16x8 wgh = *(const f16x8*)(G1T + (16 * wv + lr) * 32 + 8 * lg);
    f32x4 biGH = *(const f32x4*)(gb1 + 16 * wv + 4 * lg);
    sync_lds();                                           // S2: elev reads done
#pragma unroll
    for (int m = 0; m < 4; ++m)
        elu_store4(sHA + (16 * m + lr) * 72 + 16 * wv + 4 * lg, g3acc[m]);
    sync_lds();                                           // S3

    // ---- G4 (waves 0,1): z_E = ha @ ae_W2 + ae_b2 -> sZE ----
    if (wv < 2) {
        f32x4 acc[4];
#pragma unroll
        for (int m = 0; m < 4; ++m) acc[m] = biG4;
#pragma unroll
        for (int ks = 0; ks < 2; ++ks)
#pragma unroll
            for (int m = 0; m < 4; ++m) {
                f16x8 bf = *(const f16x8*)(sHA + (16 * m + lr) * 72 + 32 * ks + 8 * lg);
                acc[m] = MFMA16(wg4[ks], bf, acc[m]);
            }
#pragma unroll
        for (int m = 0; m < 4; ++m)
            store4(sZE + (16 * m + lr) * 32 + 16 * wv + 4 * lg, acc[m]);
    }
    // prefetch gate-logits weights/bias
    f16x8 wgl[2]; f32x4 biGL = *(const f32x4*)(GB2P + 4 * lg);
#pragma unroll
    for (int ks = 0; ks < 2; ++ks)
        wgl[ks] = *(const f16x8*)(G2T + lr * 64 + 32 * ks + 8 * lg);
    sync_lds();                                           // S4

    // ---- gate hidden: gh = elu(z_E @ gate_W1 + gate_b1), K=32 -> sHA ----
    {
        f32x4 acc[4];
#pragma unroll
        for (int m = 0; m < 4; ++m) acc[m] = biGH;
#pragma unroll
        for (int m = 0; m < 4; ++m) {
            f16x8 bf = *(const f16x8*)(sZE + (16 * m + lr) * 32 + 8 * lg);
            acc[m] = MFMA16(wgh, bf, acc[m]);
        }
#pragma unroll
        for (int m = 0; m < 4; ++m)
            elu_store4(sHA + (16 * m + lr) * 72 + 16 * wv + 4 * lg, acc[m]);
    }
    // prefetch G1 first weight quad + biases
    f16x8 wq0[4]; f32x4 biG1[4];
#pragma unroll
    for (int nt = 0; nt < 4; ++nt) {
        wq0[nt]  = *(const f16x8*)(W1T + (64 * wv + 16 * nt + lr) * 512 + 8 * lg);
        biG1[nt] = *(const f32x4*)(vb1 + 64 * wv + 16 * nt + 4 * lg);
    }
    sync_lds();                                           // S5

    // ---- gate logits (wave 0) -> sWf ; guarded (R2/R3 OOB lesson) ----
    if (wv == 0) {
        f32x4 acc[4];
#pragma unroll
        for (int m = 0; m < 4; ++m) acc[m] = biGL;
#pragma unroll
        for (int ks = 0; ks < 2; ++ks)
#pragma unroll
            for (int m = 0; m < 4; ++m) {
                f16x8 bf = *(const f16x8*)(sHA + (16 * m + lr) * 72 + 32 * ks + 8 * lg);
                acc[m] = MFMA16(wgl[ks], bf, acc[m]);
            }
        if (lg == 0) {
#pragma unroll
            for (int m = 0; m < 4; ++m)
                *(f32x4*)(sWf + (16 * m + lr) * 8) = acc[m];
        } else if (lg == 1) {
#pragma unroll
            for (int m = 0; m < 4; ++m)
                sWf[(16 * m + lr) * 8 + 4] = acc[m][0];
        }
    }
    sync_lds();                                           // S6

    // ---- softmax over 5 gate logits ----
    if (tid < 64) {
        float g[5];
#pragma unroll
        for (int e = 0; e < 5; ++e) g[e] = sWf[tid * 8 + e];
        float mx = fmaxf(fmaxf(fmaxf(g[0], g[1]), fmaxf(g[2], g[3])), g[4]);
        float s = 0.f;
#pragma unroll
        for (int e = 0; e < 5; ++e) { g[e] = __expf(g[e] - mx); s += g[e]; }
        float inv = 1.f / s;
#pragma unroll
        for (int e = 0; e < 5; ++e) sWf[tid * 8 + e] = g[e] * inv;
    }

    // ---- G1: h = elu(hist @ vae_W1 + vae_b1), K=512, double-buffered wf quads ----
    f32x4 acc1[4][4];
#pragma unroll
    for (int nt = 0; nt < 4; ++nt)
#pragma unroll
        for (int m = 0; m < 4; ++m) acc1[m][nt] = biG1[nt];
    {
        f16x8 wq1[4];
        __builtin_amdgcn_s_setprio(1);
#pragma unroll
        for (int ks2 = 0; ks2 < 8; ++ks2) {
            const int ksA = 2 * ks2, ksB = 2 * ks2 + 1;
#pragma unroll
            for (int nt = 0; nt < 4; ++nt)
                wq1[nt] = *(const f16x8*)(W1T + (64 * wv + 16 * nt + lr) * 512 + 32 * ksB + 8 * lg);
#pragma unroll
            for (int m = 0; m < 4; ++m) {
                f16x8 bf = *(const f16x8*)(sS2 + (16 * m + lr) * 488 + 32 * ksA + 8 * lg);
#pragma unroll
                for (int nt = 0; nt < 4; ++nt)
                    acc1[m][nt] = MFMA16(wq0[nt], bf, acc1[m][nt]);
            }
            if (ks2 < 7) {
#pragma unroll
                for (int nt = 0; nt < 4; ++nt)
                    wq0[nt] = *(const f16x8*)(W1T + (64 * wv + 16 * nt + lr) * 512 + 32 * (ksA + 2) + 8 * lg);
            }
#pragma unroll
            for (int m = 0; m < 4; ++m) {
                f16x8 bf = *(const f16x8*)(sS2 + (16 * m + lr) * 488 + 32 * ksB + 8 * lg);
#pragma unroll
                for (int nt = 0; nt < 4; ++nt)
                    acc1[m][nt] = MFMA16(wq1[nt], bf, acc1[m][nt]);
            }
        }
        __builtin_amdgcn_s_setprio(0);
    }
    // prefetch o_t (99 cols of S2) into regs before S2 is overwritten
    const int r_ot = tid >> 2, sub = tid & 3;
    ushort_t otv[25];
#pragma unroll
    for (int i = 0; i < 25; ++i) {
        int j = sub + 4 * i;
        if (j < 99) {
            int s;
            if (j < 3) s = j;
            else if (j < 12) { int jj = j - 3; int t = jj / 3;
                               s = 15 * (t + 1) + (jj - 3 * t); }
            else { int jj = j - 12; int t2 = jj / 29;
                   s = 164 + 145 * t2 + (jj - 29 * t2); }
            otv[i] = __builtin_bit_cast(ushort_t, sS2[r_ot * 488 + s]);
        }
    }
    // prefetch G2 weights/bias (wv<3 consumes them)
    f16x8 wzv[8]; f32x4 bzv;
    if (wv < 3) {
        bzv = *(const f32x4*)(BZV + 16 * wv + 4 * lg);
#pragma unroll
        for (int ks = 0; ks < 8; ++ks)
            wzv[ks] = *(const f16x8*)(WZV + (16 * wv + lr) * 256 + 32 * ks + 8 * lg);
    }
    sync_lds();                                           // S7: S2 reads done

    // write h (elu)
#pragma unroll
    for (int m = 0; m < 4; ++m)
#pragma unroll
        for (int nt = 0; nt < 4; ++nt)
            elu_store4(sH + (16 * m + lr) * 264 + 64 * wv + 16 * nt + 4 * lg, acc1[m][nt]);
    // assemble buf0: o_t, zeros, z_E copy
#pragma unroll
    for (int i = 0; i < 25; ++i) {
        int j = sub + 4 * i;
        if (j < 99) sB0[r_ot * 200 + 5 + j] = __builtin_bit_cast(f16, otv[i]);
    }
    {
        char* b0r = (char*)sB0 + r_ot * 400;
        if (sub == 0) { *(uint2*)(b0r + 0) = (uint2){0u, 0u}; *(ushort_t*)(b0r + 8) = 0; }
        else if (sub == 1) { *(uint2*)(b0r + 280) = (uint2){0u, 0u}; }
        else if (sub == 2) { *(uint4*)(b0r + 352) = (uint4){0u,0u,0u,0u}; }
        else               { *(uint4*)(b0r + 368) = (uint4){0u,0u,0u,0u}; }
    }
#pragma unroll
    for (int it = 0; it < 2; ++it) {   // z_E -> buf0 cols 144..175
        int idx = tid + 256 * it;
        int r = idx >> 3, c4 = idx & 7;
        uint2 v = *(uint2*)((char*)sZE + r * 64 + 8 * c4);
        *(uint2*)((char*)sB0 + r * 400 + 288 + 8 * c4) = v;
    }
    // prefetch expert0-L1 weights/bias + gate weights (we5)
    f16x8 wA[12]; f32x4 b1v[2];
#pragma unroll
    for (int ks = 0; ks < 6; ++ks)
#pragma unroll
        for (int nt = 0; nt < 2; ++nt)
            wA[ks * 2 + nt] = *(const f16x8*)(E1T + (32 * wv + 16 * nt + lr) * 192 + 32 * ks + 8 * lg);
#pragma unroll
    for (int nt = 0; nt < 2; ++nt)
        b1v[nt] = *(const f32x4*)(eb1 + 32 * wv + 16 * nt + 4 * lg);
    float we5[5];
#pragma unroll
    for (int e = 0; e < 5; ++e) we5[e] = sWf[(16 * wv + lr) * 8 + e];
    sync_lds();                                           // S8

    // ---- G2: [v_pred|z_H] = h @ Wzv + bzv, K=256, waves 0..2 -> buf0 ----
    if (wv < 3) {
        f32x4 acc[4];
#pragma unroll
        for (int m = 0; m < 4; ++m) acc[m] = bzv;
#pragma unroll
        for (int ks = 0; ks < 8; ++ks)
#pragma unroll
            for (int m = 0; m < 4; ++m) {
                f16x8 bf = *(const f16x8*)(sH + (16 * m + lr) * 264 + 32 * ks + 8 * lg);
                acc[m] = MFMA16(wzv[ks], bf, acc[m]);
            }
        int j0 = 16 * wv + 4 * lg;
        if (wv < 2 || lg == 0) {
            int col = (wv < 2) ? (108 + j0) : 104;
#pragma unroll
            for (int m = 0; m < 4; ++m)
                store4(sB0 + (16 * m + lr) * 200 + col, acc[m]);
        }
    }
    sync_lds();                                           // S9

    // ---- experts (fully unrolled; A/B/C prefetch rotation) ----
    f32x4 oacc0 = (f32x4)0.f, oacc1 = (f32x4)0.f;
#pragma unroll
    for (int e = 0; e < 5; ++e) {
        // L1: h1 = elu(inp @ eW1 + eb1)
        {
            f32x4 acc[4][2];
#pragma unroll
            for (int nt = 0; nt < 2; ++nt)
#pragma unroll
                for (int m = 0; m < 4; ++m) acc[m][nt] = b1v[nt];
            __builtin_amdgcn_s_setprio(1);
#pragma unroll
            for (int ks = 0; ks < 6; ++ks)
#pragma unroll
                for (int m = 0; m < 4; ++m) {
                    f16x8 bf = *(const f16x8*)(sB0 + (16 * m + lr) * 200 + 32 * ks + 8 * lg);
#pragma unroll
                    for (int nt = 0; nt < 2; ++nt)
                        acc[m][nt] = MFMA16(wA[ks * 2 + nt], bf, acc[m][nt]);
                }
            __builtin_amdgcn_s_setprio(0);
            // prefetch L2 weights/bias
            f16x8 wB[8]; f32x4 b2v[2];
#pragma unroll
            for (int ks = 0; ks < 4; ++ks)
#pragma unroll
                for (int nt = 0; nt < 2; ++nt)
                    wB[ks * 2 + nt] = *(const f16x8*)(E2T + (e * 128 + 32 * wv + 16 * nt + lr) * 128 + 32 * ks + 8 * lg);
#pragma unroll
            for (int nt = 0; nt < 2; ++nt)
                b2v[nt] = *(const f32x4*)(eb2 + e * 128 + 32 * wv + 16 * nt + 4 * lg);
#pragma unroll
            for (int m = 0; m < 4; ++m)
#pragma unroll
                for (int nt = 0; nt < 2; ++nt)
                    elu_store4(sH1 + (16 * m + lr) * 136 + 32 * wv + 16 * nt + 4 * lg, acc[m][nt]);
            sync_lds();
            // L2: h2 = elu(h1 @ eW2 + eb2)
            f32x4 acc2[4][2];
#pragma unroll
            for (int nt = 0; nt < 2; ++nt)
#pragma unroll
                for (int m = 0; m < 4; ++m) acc2[m][nt] = b2v[nt];
            __builtin_amdgcn_s_setprio(1);
#pragma unroll
            for (int ks = 0; ks < 4; ++ks)
#pragma unroll
                for (int m = 0; m < 4; ++m) {
                    f16x8 bf = *(const f16x8*)(sH1 + (16 * m + lr) * 136 + 32 * ks + 8 * lg);
#pragma unroll
                    for (int nt = 0; nt < 2; ++nt)
                        acc2[m][nt] = MFMA16(wB[ks * 2 + nt], bf, acc2[m][nt]);
                }
            __builtin_amdgcn_s_setprio(0);
            // prefetch L3 weights/bias
            f16x8 wC[8]; f32x4 b3v[2];
#pragma unroll
            for (int ks = 0; ks < 4; ++ks)
#pragma unroll
                for (int nt = 0; nt < 2; ++nt)
                    wC[ks * 2 + nt] = *(const f16x8*)(E3T + (e * 32 + 16 * nt + lr) * 128 + 32 * ks + 8 * lg);
#pragma unroll
            for (int nt = 0; nt < 2; ++nt)
                b3v[nt] = *(const f32x4*)(EB3P + e * 32 + 16 * nt + 4 * lg);
#pragma unroll
            for (int m = 0; m < 4; ++m)
#pragma unroll
                for (int nt = 0; nt < 2; ++nt)
                    elu_store4(sH2 + (16 * m + lr) * 136 + 32 * wv + 16 * nt + 4 * lg, acc2[m][nt]);
            sync_lds();
            // L3: acts = h2 @ eW3 + eb3 ; weighted accumulate
            f32x4 a3[2];
#pragma unroll
            for (int nt = 0; nt < 2; ++nt) a3[nt] = b3v[nt];
            __builtin_amdgcn_s_setprio(1);
#pragma unroll
            for (int ks = 0; ks < 4; ++ks) {
                f16x8 bf = *(const f16x8*)(sH2 + (16 * wv + lr) * 136 + 32 * ks + 8 * lg);
#pragma unroll
                for (int nt = 0; nt < 2; ++nt)
                    a3[nt] = MFMA16(wC[ks * 2 + nt], bf, a3[nt]);
            }
            __builtin_amdgcn_s_setprio(0);
            if (e < 4) {   // prefetch next expert's L1 weights/bias
#pragma unroll
                for (int ks = 0; ks < 6; ++ks)
#pragma unroll
                    for (int nt = 0; nt < 2; ++nt)
                        wA[ks * 2 + nt] = *(const f16x8*)(E1T + ((e + 1) * 128 + 32 * wv + 16 * nt + lr) * 192 + 32 * ks + 8 * lg);
#pragma unroll
                for (int nt = 0; nt < 2; ++nt)
                    b1v[nt] = *(const f32x4*)(eb1 + (e + 1) * 128 + 32 * wv + 16 * nt + 4 * lg);
            }
            float we = we5[e];
#pragma unroll
            for (int r = 0; r < 4; ++r) {
                oacc0[r] += we * a3[0][r];
                oacc1[r] += we * a3[1][r];
            }
            sync_lds();
        }
    }

    // ---- store out [64 x 29] fp32 ----
    {
        int row = row0 + 16 * wv + lr;
#pragma unroll
        for (int r = 0; r < 4; ++r) {
            int col0 = 4 * lg + r;
            if (col0 < 29) out[(size_t)row * 29 + col0] = oacc0[r];
            int col1 = 16 + 4 * lg + r;
            if (col1 < 29) out[(size_t)row * 29 + col1] = oacc1[r];
        }
    }
}

extern "C" void kernel_launch(void* const* d_in, const int* in_sizes, int n_in,
                              void* d_out, int out_size, void* d_ws, size_t ws_size,
                              hipStream_t stream)
{
    (void)n_in; (void)out_size; (void)ws_size;
    const float* x   = (const float*)d_in[0];
    const float* vW1 = (const float*)d_in[1];
    const float* vb1 = (const float*)d_in[2];
    const float* vWz = (const float*)d_in[3];
    const float* vbz = (const float*)d_in[4];
    const float* vWv = (const float*)d_in[5];
    const float* vbv = (const float*)d_in[6];
    const float* aW1 = (const float*)d_in[7];
    const float* ab1 = (const float*)d_in[8];
    const float* aW2 = (const float*)d_in[9];
    const float* ab2 = (const float*)d_in[10];
    const float* gW1 = (const float*)d_in[11];
    const float* gb1 = (const float*)d_in[12];
    const float* gW2 = (const float*)d_in[13];
    const float* gb2 = (const float*)d_in[14];
    const float* eW1 = (const float*)d_in[15];
    const float* eb1 = (const float*)d_in[16];
    const float* eW2 = (const float*)d_in[17];
    const float* eb2 = (const float*)d_in[18];
    const float* eW3 = (const float*)d_in[19];
    const float* eb3 = (const float*)d_in[20];

    int n = in_sizes[0] / 975;

    prep_kernel<<<(380128 + 255) / 256, 256, 0, stream>>>(
        vW1, vWz, vWv, aW1, aW2, gW1, gW2, eW1, eW2, eW3, vbz, vbv, eb3, gb2, (char*)d_ws);

    moe_fused<<<n / 64, 256, 0, stream>>>(
        x, vb1, ab1, ab2, gb1, eb1, eb2, (const char*)d_ws, (float*)d_out);
}

// Round 8
// 298.661 us; speedup vs baseline: 1.1651x; 1.0661x over previous
//
#include <hip/hip_runtime.h>
#include <math.h>

typedef _Float16 f16;
typedef f16  f16x8 __attribute__((ext_vector_type(8)));
typedef float f32x4 __attribute__((ext_vector_type(4)));
typedef unsigned short ushort_t;

#define MFMA16(a, b, c) __builtin_amdgcn_mfma_f32_16x16x32_f16((a), (b), (c), 0, 0, 0)

// ---------------- workspace layout (f16 element offsets) ----------------
#define W1T_E 0        // [256][512]  vae_W1^T, K permuted to S2 order
#define WZV_E 131072   // [48][256]   [vae_Wz | vae_Wv | 0]^T
#define A1T_E 143360   // [64][96]    ae_W1^T
#define A2T_E 149504   // [32][64]    ae_W2^T
#define G1T_E 151552   // [64][32]    gate_W1^T
#define G2T_E 153600   // [16][64]    gate_W2^T (cols 5..15 zero)
#define E1T_E 154624   // [5][128][192] eW1^T, K remapped to padded-192 buf0 layout
#define E2T_E 277504   // [5][128][128] eW2^T
#define E3T_E 359424   // [5][32][128]  eW3^T, cols 29..31 zero
#define F32_B 759808   // f32 appendix: BZV[48] | EB3P[160] | GB2P[16]

// ---------------- LDS layout (bytes), 64-row tile, 2 blocks/CU ----------------
#define S2_OFF   0
#define B0_OFF   36864
#define H2_OFF   17408
#define ELEV_OFF 62528
#define HA_OFF   62528
#define ZE_OFF   71744
#define WF_OFF   75840  // [64][8] f32 gate weights
#define SMEM_SZ  77888  // 2 x 77888 <= 163840 -> 2 blocks/CU (512 thr: 16 waves/CU)

__device__ __forceinline__ float elu_f(float v) {
    float e = __expf(v) - 1.f;
    return v > 0.f ? v : e;
}

// round-to-nearest f32x2 -> packed f16x2 (RTZ pkrtz biased the chain; keep RTN)
__device__ __forceinline__ unsigned pk(float a, float b) {
    ushort_t u0 = __builtin_bit_cast(ushort_t, (f16)a);
    ushort_t u1 = __builtin_bit_cast(ushort_t, (f16)b);
    return (unsigned)u0 | ((unsigned)u1 << 16);
}

__device__ __forceinline__ void store4(f16* p, f32x4 v) {
    uint2 t; t.x = pk(v[0], v[1]); t.y = pk(v[2], v[3]);
    *(uint2*)p = t;
}

__device__ __forceinline__ void elu_store4(f16* p, f32x4 v) {
    uint2 t; t.x = pk(elu_f(v[0]), elu_f(v[1])); t.y = pk(elu_f(v[2]), elu_f(v[3]));
    *(uint2*)p = t;
}

// LDS-only barrier: drains DS ops but leaves global loads in flight.
__device__ __forceinline__ void sync_lds() {
    asm volatile("s_waitcnt lgkmcnt(0)" ::: "memory");
    __builtin_amdgcn_s_barrier();
    asm volatile("" ::: "memory");
    __builtin_amdgcn_sched_barrier(0);
}

// ---------------- weight repack: fp32 -> f16, transposed/padded/permuted ----------------
__global__ void prep_kernel(const float* __restrict__ vW1, const float* __restrict__ vWz,
                            const float* __restrict__ vWv, const float* __restrict__ aW1,
                            const float* __restrict__ aW2, const float* __restrict__ gW1,
                            const float* __restrict__ gW2, const float* __restrict__ eW1,
                            const float* __restrict__ eW2, const float* __restrict__ eW3,
                            const float* __restrict__ vbz, const float* __restrict__ vbv,
                            const float* __restrict__ eb3, const float* __restrict__ gb2,
                            char* __restrict__ ws)
{
    int i = blockIdx.x * 256 + threadIdx.x;
    f16* H = (f16*)ws;
    if (i < 131072) {                                   // W1T [c=256][ks=512], S2-order K
        int c = i >> 9, ks = i & 511;
        int xcol = 12 + ks;
        float v = 0.f;
        if (xcol >= 15 && xcol <= 494) {
            int hc;
            if (xcol < 60) {
                int t = xcol / 15; int rm = xcol - 15 * t; int f = rm / 3;
                hc = 96 * f + 3 * (t - 1) + (rm - 3 * f);
            } else {
                int t2 = (xcol - 60) / 145; int rm = xcol - 60 - 145 * t2; int f = rm / 29;
                hc = 96 * f + 9 + 29 * t2 + (rm - 29 * f);
            }
            v = vW1[hc * 256 + c];
        }
        H[i] = (f16)v;
    } else if (i < 143360) {                            // WZV [c=48][k=256]
        int j = i - 131072; int c = j / 256, k = j - c * 256;
        float v = (c < 32) ? vWz[k * 32 + c] : ((c < 35) ? vWv[k * 3 + (c - 32)] : 0.f);
        H[i] = (f16)v;
    } else if (i < 149504) {                            // A1T [c=64][k=96]
        int j = i - 143360; int c = j / 96, k = j - c * 96;
        H[i] = (f16)aW1[k * 64 + c];
    } else if (i < 151552) {                            // A2T [c=32][k=64]
        int j = i - 149504; int c = j / 64, k = j - c * 64;
        H[i] = (f16)aW2[k * 32 + c];
    } else if (i < 153600) {                            // G1T [c=64][k=32]
        int j = i - 151552; int c = j / 32, k = j - c * 32;
        H[i] = (f16)gW1[k * 64 + c];
    } else if (i < 154624) {                            // G2T [c=16][k=64]
        int j = i - 153600; int c = j / 64, k = j - c * 64;
        H[i] = (f16)((c < 5) ? gW2[k * 5 + c] : 0.f);
    } else if (i < 277504) {                            // E1T [e][c=128][k=192] remapped
        int j = i - 154624; int e = j / 24576, jj = j - e * 24576;
        int c = jj / 192, k = jj - c * 192;
        int ko = (k >= 5 && k < 107)   ? (k - 5)
               : (k >= 108 && k < 140) ? (k - 6)
               : (k >= 144 && k < 176) ? (k - 10) : -1;
        H[i] = (f16)((ko >= 0) ? eW1[(e * 166 + ko) * 128 + c] : 0.f);
    } else if (i < 359424) {                            // E2T [e][c=128][k=128]
        int j = i - 277504; int e = j / 16384, jj = j - e * 16384;
        int c = jj / 128, k = jj - c * 128;
        H[i] = (f16)eW2[(e * 128 + k) * 128 + c];
    } else if (i < 379904) {                            // E3T [e][c=32][k=128]
        int j = i - 359424; int e = j / 4096, jj = j - e * 4096;
        int c = jj / 128, k = jj - c * 128;
        H[i] = (f16)((c < 29) ? eW3[(e * 128 + k) * 29 + c] : 0.f);
    } else if (i < 380128) {                            // f32 appendix
        int j = i - 379904;
        float* F = (float*)(ws + F32_B);
        float v;
        if (j < 48)       v = (j < 32) ? vbz[j] : ((j < 35) ? vbv[j - 32] : 0.f);
        else if (j < 208) { int t = j - 48; int e = t >> 5, c = t & 31;
                            v = (c < 29) ? eb3[e * 29 + c] : 0.f; }
        else              { int t = j - 208; v = (t < 5) ? gb2[t] : 0.f; }
        F[j] = v;
    }
}

// ---------------- fused actor: 64 rows/block, 512 threads (8 waves) ----------------
__global__ __launch_bounds__(512, 4) void moe_fused(
    const float* __restrict__ x,
    const float* __restrict__ vb1,
    const float* __restrict__ ab1,
    const float* __restrict__ ab2,
    const float* __restrict__ gb1,
    const float* __restrict__ eb1,
    const float* __restrict__ eb2,
    const char* __restrict__ ws,
    float* __restrict__ out)
{
    __shared__ __align__(16) char smem[SMEM_SZ];
    const int tid  = threadIdx.x;
    const int wv   = tid >> 6;      // 0..7
    const int lane = tid & 63;
    const int lr   = lane & 15;
    const int lg   = lane >> 4;
    const int wh   = wv & 1;        // row-half for half-phases
    const int wc   = wv >> 1;       // col-quarter 0..3
    const int row0 = (int)blockIdx.x * 64;

    const f16* W1T = (const f16*)ws + W1T_E;
    const f16* WZV = (const f16*)ws + WZV_E;
    const f16* A1T = (const f16*)ws + A1T_E;
    const f16* A2T = (const f16*)ws + A2T_E;
    const f16* G1T = (const f16*)ws + G1T_E;
    const f16* G2T = (const f16*)ws + G2T_E;
    const f16* E1T = (const f16*)ws + E1T_E;
    const f16* E2T = (const f16*)ws + E2T_E;
    const f16* E3T = (const f16*)ws + E3T_E;
    const float* BZV  = (const float*)(ws + F32_B);
    const float* EB3P = BZV + 48;
    const float* GB2P = BZV + 208;

    f16* sS2 = (f16*)(smem + S2_OFF);     // stride 488
    f16* sEl = (f16*)(smem + ELEV_OFF);   // stride 104
    f16* sHA = (f16*)(smem + HA_OFF);     // stride 72 (ha, then gh)
    f16* sZE = (f16*)(smem + ZE_OFF);     // stride 32
    f16* sH  = (f16*)(smem + S2_OFF);     // stride 264 (after G1)
    f16* sB0 = (f16*)(smem + B0_OFF);     // stride 200 (after G1)
    f16* sH1 = (f16*)(smem + S2_OFF);     // stride 136 (experts)
    f16* sH2 = (f16*)(smem + H2_OFF);     // stride 136
    float* sWf = (float*)(smem + WF_OFF); // stride 8 f32

    // ---- P0: coalesced staging of S2 + elev (8 rows per wave) ----
    {
        if (tid < 16) *(unsigned*)(smem + 62464 + 4 * tid) = 0u;  // S2 tail pad
        const int sr0 = wv * 8;
        for (int rr = 0; rr < 8; ++rr) {
            const int r = sr0 + rr;
            const float* xr = x + (size_t)(row0 + r) * 975;
            if (lane < 48) {
                float a = xr[879 + 2 * lane], b = xr[880 + 2 * lane];
                *(unsigned*)(sEl + r * 104 + 2 * lane) = pk(a, b);
            }
            f16* dst = sS2 + r * 488;
#pragma unroll
            for (int j = 0; j < 4; ++j) {
                int p = j * 64 + lane;
                if (p < 244) {
                    float a = 0.f, b = 0.f;
                    if (p < 242) { a = xr[12 + 2 * p]; b = xr[13 + 2 * p]; }
                    *(unsigned*)(dst + 2 * p) = pk(a, b);
                }
            }
        }
    }
    sync_lds();                                           // S1

    // ---- G3: ha = elu(e_t @ ae_W1 + ae_b1), cols split 4 ways, rows halved ----
    f32x4 g3acc[2];
    {
        f32x4 bi = *(const f32x4*)(ab1 + 16 * wc + 4 * lg);
        g3acc[0] = bi; g3acc[1] = bi;
#pragma unroll
        for (int ks = 0; ks < 3; ++ks) {
            f16x8 wf = *(const f16x8*)(A1T + (16 * wc + lr) * 96 + 32 * ks + 8 * lg);
#pragma unroll
            for (int mm = 0; mm < 2; ++mm) {
                int m = 2 * wh + mm;
                f16x8 bf = *(const f16x8*)(sEl + (16 * m + lr) * 104 + 32 * ks + 8 * lg);
                g3acc[mm] = MFMA16(wf, bf, g3acc[mm]);
            }
        }
    }
    sync_lds();                                           // S2: elev reads done
#pragma unroll
    for (int mm = 0; mm < 2; ++mm)
        elu_store4(sHA + (16 * (2 * wh + mm) + lr) * 72 + 16 * wc + 4 * lg, g3acc[mm]);
    sync_lds();                                           // S3

    // ---- G4 (waves 0..3): z_E = ha @ ae_W2 + ae_b2 -> sZE ----
    if (wv < 4) {
        int c = wv >> 1, h = wv & 1;
        f32x4 bi = *(const f32x4*)(ab2 + 16 * c + 4 * lg);
        f32x4 acc[2]; acc[0] = bi; acc[1] = bi;
#pragma unroll
        for (int ks = 0; ks < 2; ++ks) {
            f16x8 wf = *(const f16x8*)(A2T + (16 * c + lr) * 64 + 32 * ks + 8 * lg);
#pragma unroll
            for (int mm = 0; mm < 2; ++mm) {
                int m = 2 * h + mm;
                f16x8 bf = *(const f16x8*)(sHA + (16 * m + lr) * 72 + 32 * ks + 8 * lg);
                acc[mm] = MFMA16(wf, bf, acc[mm]);
            }
        }
#pragma unroll
        for (int mm = 0; mm < 2; ++mm)
            store4(sZE + (16 * (2 * h + mm) + lr) * 32 + 16 * c + 4 * lg, acc[mm]);
    }
    sync_lds();                                           // S4

    // ---- gate hidden: gh = elu(z_E @ gate_W1 + gate_b1), K=32 -> sHA ----
    {
        f32x4 bi = *(const f32x4*)(gb1 + 16 * wc + 4 * lg);
        f32x4 acc[2]; acc[0] = bi; acc[1] = bi;
        f16x8 wf = *(const f16x8*)(G1T + (16 * wc + lr) * 32 + 8 * lg);
#pragma unroll
        for (int mm = 0; mm < 2; ++mm) {
            int m = 2 * wh + mm;
            f16x8 bf = *(const f16x8*)(sZE + (16 * m + lr) * 32 + 8 * lg);
            acc[mm] = MFMA16(wf, bf, acc[mm]);
        }
#pragma unroll
        for (int mm = 0; mm < 2; ++mm)
            elu_store4(sHA + (16 * (2 * wh + mm) + lr) * 72 + 16 * wc + 4 * lg, acc[mm]);
    }
    sync_lds();                                           // S5

    // ---- gate logits (wave 0) -> sWf ; guarded (R2/R3 OOB lesson) ----
    if (wv == 0) {
        f32x4 bi = *(const f32x4*)(GB2P + 4 * lg);
        f32x4 acc[4];
#pragma unroll
        for (int m = 0; m < 4; ++m) acc[m] = bi;
#pragma unroll
        for (int ks = 0; ks < 2; ++ks) {
            f16x8 wf = *(const f16x8*)(G2T + lr * 64 + 32 * ks + 8 * lg);
#pragma unroll
            for (int m = 0; m < 4; ++m) {
                f16x8 bf = *(const f16x8*)(sHA + (16 * m + lr) * 72 + 32 * ks + 8 * lg);
                acc[m] = MFMA16(wf, bf, acc[m]);
            }
        }
        if (lg == 0) {
#pragma unroll
            for (int m = 0; m < 4; ++m)
                *(f32x4*)(sWf + (16 * m + lr) * 8) = acc[m];
        } else if (lg == 1) {
#pragma unroll
            for (int m = 0; m < 4; ++m)
                sWf[(16 * m + lr) * 8 + 4] = acc[m][0];
        }
    }
    sync_lds();                                           // S6

    // ---- softmax over 5 gate logits ----
    if (tid < 64) {
        float g[5];
#pragma unroll
        for (int e = 0; e < 5; ++e) g[e] = sWf[tid * 8 + e];
        float mx = fmaxf(fmaxf(fmaxf(g[0], g[1]), fmaxf(g[2], g[3])), g[4]);
        float s = 0.f;
#pragma unroll
        for (int e = 0; e < 5; ++e) { g[e] = __expf(g[e] - mx); s += g[e]; }
        float inv = 1.f / s;
#pragma unroll
        for (int e = 0; e < 5; ++e) sWf[tid * 8 + e] = g[e] * inv;
    }

    // ---- G1: h = elu(hist @ vae_W1 + vae_b1), K=512; 32 cols/wave (2 nt) ----
    f32x4 acc1[4][2];
#pragma unroll
    for (int nt = 0; nt < 2; ++nt) {
        f32x4 bi = *(const f32x4*)(vb1 + 32 * wv + 16 * nt + 4 * lg);
#pragma unroll
        for (int m = 0; m < 4; ++m) acc1[m][nt] = bi;
    }
    __builtin_amdgcn_s_setprio(1);
#pragma unroll
    for (int ks = 0; ks < 16; ++ks) {
        f16x8 wf[2];
#pragma unroll
        for (int nt = 0; nt < 2; ++nt)
            wf[nt] = *(const f16x8*)(W1T + (32 * wv + 16 * nt + lr) * 512 + 32 * ks + 8 * lg);
#pragma unroll
        for (int m = 0; m < 4; ++m) {
            f16x8 bf = *(const f16x8*)(sS2 + (16 * m + lr) * 488 + 32 * ks + 8 * lg);
#pragma unroll
            for (int nt = 0; nt < 2; ++nt)
                acc1[m][nt] = MFMA16(wf[nt], bf, acc1[m][nt]);
        }
    }
    __builtin_amdgcn_s_setprio(0);
    // prefetch o_t (99 cols of S2) into regs before S2 is overwritten
    const int r_ot = tid >> 3, sub = tid & 7;
    ushort_t otv[13];
#pragma unroll
    for (int i = 0; i < 13; ++i) {
        int j = sub + 8 * i;
        if (j < 99) {
            int s;
            if (j < 3) s = j;
            else if (j < 12) { int jj = j - 3; int t = jj / 3;
                               s = 15 * (t + 1) + (jj - 3 * t); }
            else { int jj = j - 12; int t2 = jj / 29;
                   s = 164 + 145 * t2 + (jj - 29 * t2); }
            otv[i] = __builtin_bit_cast(ushort_t, sS2[r_ot * 488 + s]);
        }
    }
    float we5[5];
    sync_lds();                                           // S7: S2 reads done

    // write h (elu)
#pragma unroll
    for (int m = 0; m < 4; ++m)
#pragma unroll
        for (int nt = 0; nt < 2; ++nt)
            elu_store4(sH + (16 * m + lr) * 264 + 32 * wv + 16 * nt + 4 * lg, acc1[m][nt]);
    // assemble buf0: o_t, zeros, z_E copy
#pragma unroll
    for (int i = 0; i < 13; ++i) {
        int j = sub + 8 * i;
        if (j < 99) sB0[r_ot * 200 + 5 + j] = __builtin_bit_cast(f16, otv[i]);
    }
    {
        char* b0r = (char*)sB0 + r_ot * 400;
        if (sub == 0) { *(uint2*)(b0r + 0) = (uint2){0u, 0u}; *(ushort_t*)(b0r + 8) = 0; }
        else if (sub == 1) { *(uint2*)(b0r + 280) = (uint2){0u, 0u}; }
        else if (sub == 2) { *(uint4*)(b0r + 352) = (uint4){0u,0u,0u,0u}; }
        else if (sub == 3) { *(uint4*)(b0r + 368) = (uint4){0u,0u,0u,0u}; }
    }
    {   // z_E -> buf0 cols 144..175 (512 quads, 1 per thread)
        int r = tid >> 3, c4 = tid & 7;
        uint2 v = *(uint2*)((char*)sZE + r * 64 + 8 * c4);
        *(uint2*)((char*)sB0 + r * 400 + 288 + 8 * c4) = v;
    }
#pragma unroll
    for (int e = 0; e < 5; ++e) we5[e] = sWf[(16 * (wv & 3) + lr) * 8 + e];
    sync_lds();                                           // S8

    // ---- G2: [v_pred|z_H] = h @ Wzv + bzv, K=256; waves 0..5 -> buf0 ----
    if (wv < 6) {
        int c = wv >> 1, h = wv & 1;
        f32x4 bz = *(const f32x4*)(BZV + 16 * c + 4 * lg);
        f32x4 acc[2]; acc[0] = bz; acc[1] = bz;
#pragma unroll
        for (int ks = 0; ks < 8; ++ks) {
            f16x8 wf = *(const f16x8*)(WZV + (16 * c + lr) * 256 + 32 * ks + 8 * lg);
#pragma unroll
            for (int mm = 0; mm < 2; ++mm) {
                int m = 2 * h + mm;
                f16x8 bf = *(const f16x8*)(sH + (16 * m + lr) * 264 + 32 * ks + 8 * lg);
                acc[mm] = MFMA16(wf, bf, acc[mm]);
            }
        }
        if (c < 2 || lg == 0) {
            int col = (c < 2) ? (108 + 16 * c + 4 * lg) : 104;
#pragma unroll
            for (int mm = 0; mm < 2; ++mm)
                store4(sB0 + (16 * (2 * h + mm) + lr) * 200 + col, acc[mm]);
        }
    }
    sync_lds();                                           // S9

    // ---- experts: 5 x (L1 K=192, L2 K=128, L3 K=128); 16 cols/wave ----
    f32x4 oacc = (f32x4)0.f;
    const int mrow = wv & 3;        // L3 row-tile
    const int nt3  = wv >> 2;       // L3 col-tile

    for (int e = 0; e < 5; ++e) {
        // L1: h1 = elu(inp @ eW1 + eb1), col-tile = wv
        {
            f32x4 bi = *(const f32x4*)(eb1 + e * 128 + 16 * wv + 4 * lg);
            f32x4 acc[4];
#pragma unroll
            for (int m = 0; m < 4; ++m) acc[m] = bi;
            __builtin_amdgcn_s_setprio(1);
#pragma unroll
            for (int ks = 0; ks < 6; ++ks) {
                f16x8 wf = *(const f16x8*)(E1T + (e * 128 + 16 * wv + lr) * 192 + 32 * ks + 8 * lg);
#pragma unroll
                for (int m = 0; m < 4; ++m) {
                    f16x8 bf = *(const f16x8*)(sB0 + (16 * m + lr) * 200 + 32 * ks + 8 * lg);
                    acc[m] = MFMA16(wf, bf, acc[m]);
                }
            }
            __builtin_amdgcn_s_setprio(0);
#pragma unroll
            for (int m = 0; m < 4; ++m)
                elu_store4(sH1 + (16 * m + lr) * 136 + 16 * wv + 4 * lg, acc[m]);
        }
        sync_lds();
        // L2: h2 = elu(h1 @ eW2 + eb2), col-tile = wv
        {
            f32x4 bi = *(const f32x4*)(eb2 + e * 128 + 16 * wv + 4 * lg);
            f32x4 acc[4];
#pragma unroll
            for (int m = 0; m < 4; ++m) acc[m] = bi;
            __builtin_amdgcn_s_setprio(1);
#pragma unroll
            for (int ks = 0; ks < 4; ++ks) {
                f16x8 wf = *(const f16x8*)(E2T + (e * 128 + 16 * wv + lr) * 128 + 32 * ks + 8 * lg);
#pragma unroll
                for (int m = 0; m < 4; ++m) {
                    f16x8 bf = *(const f16x8*)(sH1 + (16 * m + lr) * 136 + 32 * ks + 8 * lg);
                    acc[m] = MFMA16(wf, bf, acc[m]);
                }
            }
            __builtin_amdgcn_s_setprio(0);
#pragma unroll
            for (int m = 0; m < 4; ++m)
                elu_store4(sH2 + (16 * m + lr) * 136 + 16 * wv + 4 * lg, acc[m]);
        }
        sync_lds();
        // L3: acts = h2 @ eW3 + eb3; rows 16*mrow, cols 16*nt3; weighted accumulate
        {
            f32x4 a3 = *(const f32x4*)(EB3P + e * 32 + 16 * nt3 + 4 * lg);
#pragma unroll
            for (int ks = 0; ks < 4; ++ks) {
                f16x8 bf = *(const f16x8*)(sH2 + (16 * mrow + lr) * 136 + 32 * ks + 8 * lg);
                f16x8 wf = *(const f16x8*)(E3T + (e * 32 + 16 * nt3 + lr) * 128 + 32 * ks + 8 * lg);
                a3 = MFMA16(wf, bf, a3);
            }
            float we = we5[e];
#pragma unroll
            for (int r = 0; r < 4; ++r) oacc[r] += we * a3[r];
        }
        sync_lds();
    }

    // ---- store out [64 x 29] fp32: row 16*mrow+lr, cols 16*nt3+4lg+r ----
    {
        int row = row0 + 16 * mrow + lr;
#pragma unroll
        for (int r = 0; r < 4; ++r) {
            int col = 16 * nt3 + 4 * lg + r;
            if (col < 29) out[(size_t)row * 29 + col] = oacc[r];
        }
    }
}

extern "C" void kernel_launch(void* const* d_in, const int* in_sizes, int n_in,
                              void* d_out, int out_size, void* d_ws, size_t ws_size,
                              hipStream_t stream)
{
    (void)n_in; (void)out_size; (void)ws_size;
    const float* x   = (const float*)d_in[0];
    const float* vW1 = (const float*)d_in[1];
    const float* vb1 = (const float*)d_in[2];
    const float* vWz = (const float*)d_in[3];
    const float* vbz = (const float*)d_in[4];
    const float* vWv = (const float*)d_in[5];
    const float* vbv = (const float*)d_in[6];
    const float* aW1 = (const float*)d_in[7];
    const float* ab1 = (const float*)d_in[8];
    const float* aW2 = (const float*)d_in[9];
    const float* ab2 = (const float*)d_in[10];
    const float* gW1 = (const float*)d_in[11];
    const float* gb1 = (const float*)d_in[12];
    const float* gW2 = (const float*)d_in[13];
    const float* gb2 = (const float*)d_in[14];
    const float* eW1 = (const float*)d_in[15];
    const float* eb1 = (const float*)d_in[16];
    const float* eW2 = (const float*)d_in[17];
    const float* eb2 = (const float*)d_in[18];
    const float* eW3 = (const float*)d_in[19];
    const float* eb3 = (const float*)d_in[20];

    int n = in_sizes[0] / 975;

    prep_kernel<<<(380128 + 255) / 256, 256, 0, stream>>>(
        vW1, vWz, vWv, aW1, aW2, gW1, gW2, eW1, eW2, eW3, vbz, vbv, eb3, gb2, (char*)d_ws);

    moe_fused<<<n / 64, 512, 0, stream>>>(
        x, vb1, ab1, ab2, gb1, eb1, eb2, (const char*)d_ws, (float*)d_out);
}